// Round 13
// baseline (313.522 us; speedup 1.0000x reference)
//
#include <hip/hip_runtime.h>

typedef unsigned short u16;
typedef unsigned int u32;
typedef __bf16 bf16x8 __attribute__((ext_vector_type(8)));
typedef float f32x4 __attribute__((ext_vector_type(4)));

#define S_LEN 2048

__device__ __forceinline__ u16 f2b(float f) {
    union { float f; unsigned u; } a; a.f = f;
    unsigned u = a.u;
    unsigned r = u + 0x7fffu + ((u >> 16) & 1u);
    return (u16)(r >> 16);
}

__device__ __forceinline__ u32 pk2(float a, float b) {
    return (u32)f2b(a) | ((u32)f2b(b) << 16);
}

__device__ __forceinline__ void gload16(const void* g, void* l) {
    __builtin_amdgcn_global_load_lds(
        (const __attribute__((address_space(1))) unsigned int*)g,
        (__attribute__((address_space(3))) unsigned int*)l,
        16, 0, 0);
}

// ---------- x f32 -> bf16 ----------
__global__ __launch_bounds__(256) void conv_x_kernel(const float* __restrict__ x,
                                                     u16* __restrict__ xb) {
    long i = ((long)blockIdx.x * 256 + threadIdx.x) * 4;
    float4 v = *(const float4*)(x + i);
    ushort4 o;
    o.x = f2b(v.x); o.y = f2b(v.y); o.z = f2b(v.z); o.w = f2b(v.w);
    *(ushort4*)(xb + i) = o;
}

// ---------- transpose-pack wq|wk|wv -> W[768][4096] bf16 (LDS 32x32 tiles) ----------
__global__ __launch_bounds__(256) void pack_wqkv_kernel(const float* __restrict__ wq,
                                                        const float* __restrict__ wk,
                                                        const float* __restrict__ wv,
                                                        u16* __restrict__ W) {
    __shared__ float t[32][33];
    const int n0 = blockIdx.x * 32, k0 = blockIdx.y * 32;
    const int tid = threadIdx.x;
    const int cc = tid & 31, rr = tid >> 5;
    #pragma unroll
    for (int i = 0; i < 4; ++i) {
        int k = k0 + rr + i * 8, n = n0 + cc;
        float v;
        if (n < 512)      v = wq[(size_t)k * 512 + n];
        else if (n < 640) v = wk[(size_t)k * 128 + (n - 512)];
        else              v = wv[(size_t)k * 128 + (n - 640)];
        t[rr + i * 8][cc] = v;
    }
    __syncthreads();
    #pragma unroll
    for (int i = 0; i < 4; ++i) {
        int nn = rr + i * 8, kk = cc;
        W[(size_t)(n0 + nn) * 4096 + k0 + kk] = f2b(t[kk][nn]);
    }
}

// ---------- transpose-pack wo[512][4096] -> WoT[4096][512] bf16 ----------
__global__ __launch_bounds__(256) void pack_wo_kernel(const float* __restrict__ wo,
                                                      u16* __restrict__ W) {
    __shared__ float t[32][33];
    const int n0 = blockIdx.x * 32, k0 = blockIdx.y * 32;
    const int tid = threadIdx.x;
    const int cc = tid & 31, rr = tid >> 5;
    #pragma unroll
    for (int i = 0; i < 4; ++i)
        t[rr + i * 8][cc] = wo[(size_t)(k0 + rr + i * 8) * 4096 + n0 + cc];
    __syncthreads();
    #pragma unroll
    for (int i = 0; i < 4; ++i)
        W[(size_t)(n0 + rr + i * 8) * 512 + k0 + cc] = f2b(t[cc][rr + i * 8]);
}

// ---------- GEMM: C = A(MxK,bf16) * B^T(NxK,bf16), counted-vmcnt 3-deep ring (r10) ----------
__global__ __launch_bounds__(256) void gemm_pipe(const u16* __restrict__ A,
                                                 const u16* __restrict__ B,
                                                 float* __restrict__ C0,
                                                 float* __restrict__ C1,
                                                 int N, int K, int kBase) {
    __shared__ __align__(16) u16 sA[3][128 * 32];
    __shared__ __align__(16) u16 sB[3][128 * 32];
    const int tid = threadIdx.x;
    const int lane = tid & 63, wid = tid >> 6;
    const int wr = wid >> 1, wc = wid & 1;
    const int l15 = lane & 15, g = lane >> 4;
    const int srow = lane >> 2;
    const int swzc = ((lane & 3) * 8) ^ (((lane >> 3) & 3) << 3);
    const int rswz = ((l15 >> 1) & 3) << 3;

    const u32 lid = blockIdx.x + gridDim.x * (blockIdx.y + gridDim.y * blockIdx.z);
    const u32 xcd = lid & 7, slot = lid >> 3;
    const u32 per = gridDim.x * gridDim.z;
    const u32 bml = slot / per;
    const u32 rmd = slot - bml * per;
    const int bn = rmd % gridDim.x;
    const int z  = rmd / gridDim.x;
    const int bm = xcd * (gridDim.y >> 3) + bml;

    float* C = z ? C1 : C0;
    const int k0 = z * kBase;
    const int nt = kBase / 32;

    const int ch0 = wid * 2, ch1 = wid * 2 + 1;
    const int r0 = ch0 * 16 + srow, r1 = ch1 * 16 + srow;

    auto stage = [&](int buf, int kt) {
        gload16(&A[(size_t)(bm * 128 + r0) * K + kt + swzc], &sA[buf][ch0 * 512]);
        gload16(&A[(size_t)(bm * 128 + r1) * K + kt + swzc], &sA[buf][ch1 * 512]);
        gload16(&B[(size_t)(bn * 128 + r0) * K + kt + swzc], &sB[buf][ch0 * 512]);
        gload16(&B[(size_t)(bn * 128 + r1) * K + kt + swzc], &sB[buf][ch1 * 512]);
    };

    f32x4 acc[4][4] = {};

    stage(0, k0);
    stage(1, k0 + 32);

    for (int t = 0; t < nt; ++t) {
        if (t + 1 < nt) asm volatile("s_waitcnt vmcnt(4)" ::: "memory");
        else            asm volatile("s_waitcnt vmcnt(0)" ::: "memory");
        __builtin_amdgcn_s_barrier();
        __builtin_amdgcn_sched_barrier(0);
        if (t + 2 < nt) stage((t + 2) % 3, k0 + (t + 2) * 32);
        const int cur = t % 3;
        bf16x8 af[4], bfr[4];
        #pragma unroll
        for (int m = 0; m < 4; ++m)
            af[m] = *(const bf16x8*)&sA[cur][(wr * 64 + m * 16 + l15) * 32 + (g * 8 ^ rswz)];
        #pragma unroll
        for (int n = 0; n < 4; ++n)
            bfr[n] = *(const bf16x8*)&sB[cur][(wc * 64 + n * 16 + l15) * 32 + (g * 8 ^ rswz)];
        #pragma unroll
        for (int m = 0; m < 4; ++m)
            #pragma unroll
            for (int n = 0; n < 4; ++n)
                acc[m][n] = __builtin_amdgcn_mfma_f32_16x16x32_bf16(af[m], bfr[n], acc[m][n], 0, 0, 0);
    }

    #pragma unroll
    for (int m = 0; m < 4; ++m) {
        int row = bm * 128 + wr * 64 + m * 16 + g * 4;
        #pragma unroll
        for (int n = 0; n < 4; ++n) {
            int col = bn * 128 + wc * 64 + n * 16 + l15;
            #pragma unroll
            for (int rr = 0; rr < 4; ++rr)
                C[(size_t)(row + rr) * N + col] = acc[m][n][rr];
        }
    }
}

// ---------- RoPE + RMSNorm + scales: (P0+P1)(f32) -> Qb/Kb (bf16) ----------
__global__ __launch_bounds__(256) void rope_rms_kernel(const float* __restrict__ P0,
                                                       const float* __restrict__ P1,
                                                       const int* __restrict__ positions,
                                                       u16* __restrict__ Qb,
                                                       u16* __restrict__ Kb) {
    const int w = blockIdx.x * 4 + (threadIdx.x >> 6);
    const int lane = threadIdx.x & 63;
    const int row = w / 5, head = w - row * 5;
    const int s = row & (S_LEN - 1);

    float pos = (float)positions[s];
    float ex = (float)(2 * lane) * (1.0f / 128.0f);
    float inv_freq = __expf(-ex * 13.122363377404328f);   // ln(500000)
    float ang = pos * inv_freq;
    float c, sn;
    __sincosf(ang, &sn, &c);

    size_t off = (size_t)row * 768 + head * 128 + 2 * lane;
    float2 va = *(const float2*)&P0[off];
    float2 vb = *(const float2*)&P1[off];
    float x0 = va.x + vb.x, x1 = va.y + vb.y;
    float o0 = x0 * c - x1 * sn;
    float o1 = x0 * sn + x1 * c;

    float ss = o0 * o0 + o1 * o1;
    #pragma unroll
    for (int m = 1; m < 64; m <<= 1) ss += __shfl_xor(ss, m, 64);
    float rms = rsqrtf(ss * (1.0f / 128.0f) + 1e-6f);

    if (head < 4) {
        float ascale = logf(floorf((pos + 1.0f) * (1.0f / 8192.0f)) + 1.0f) * 0.1f + 1.0f;
        // fold 1/sqrt(128) * (1/ln2) so attention uses exp2
        float mult = rms * ascale * 0.12751743f;
        *(u32*)&Qb[(size_t)row * 512 + head * 128 + 2 * lane] = pk2(o0 * mult, o1 * mult);
    } else {
        *(u32*)&Kb[(size_t)row * 128 + 2 * lane] = pk2(o0 * rms, o1 * rms);
    }
}

// ---------- V slice of (P0+P1) -> Vt[b][d][s] bf16 (LDS tile transpose) ----------
__global__ __launch_bounds__(256) void vtrans_kernel(const float* __restrict__ P0,
                                                     const float* __restrict__ P1,
                                                     u16* __restrict__ Vt) {
    __shared__ u16 tile[128][72];
    const int bi = blockIdx.x >> 5, st = blockIdx.x & 31;
    const int s0 = st * 64;
    const int tid = threadIdx.x;
    #pragma unroll
    for (int i = 0; i < 8; ++i) {
        int idx = i * 256 + tid;
        int r = idx >> 5, c4 = idx & 31;
        size_t off = (size_t)(bi * S_LEN + s0 + r) * 768 + 640 + c4 * 4;
        float4 a = *(const float4*)&P0[off];
        float4 b = *(const float4*)&P1[off];
        tile[c4 * 4 + 0][r] = f2b(a.x + b.x);
        tile[c4 * 4 + 1][r] = f2b(a.y + b.y);
        tile[c4 * 4 + 2][r] = f2b(a.z + b.z);
        tile[c4 * 4 + 3][r] = f2b(a.w + b.w);
    }
    __syncthreads();
    #pragma unroll
    for (int i = 0; i < 4; ++i) {
        int idx = i * 256 + tid;
        int d = idx >> 3, sl = idx & 7;
        bf16x8 v = *(const bf16x8*)&tile[d][sl * 8];
        *(bf16x8*)&Vt[((size_t)bi * 128 + d) * S_LEN + s0 + sl * 8] = v;
    }
}

// ---------- flash attention (causal, GQA 4:1) ----------
// block = (b, q-tile of 16); 4 waves = 4 heads sharing LDS-staged K (dbuf, swizzled).
// V^T read DIRECTLY from global (L2-resident 512KB/batch; m169 lesson: don't LDS-stage
// cache-fitting data). LDS 41.75KB -> 3 blocks/CU (12 waves/CU).
__global__ __launch_bounds__(256) void attn_kernel(const u16* __restrict__ Qb,
                                                   const u16* __restrict__ Kb,
                                                   const u16* __restrict__ Vt,
                                                   u16* __restrict__ Ob) {
    __shared__ __align__(16) u16 sK[2][64 * 128];
    __shared__ __align__(16) u32 p_all[4][16 * 36];
    const int tid = threadIdx.x;
    const int lane = tid & 63, wid = tid >> 6;    // wid = head
    const int l15 = lane & 15, g = lane >> 4;
    const int bid = blockIdx.x;
    const int qt = 127 - (bid >> 2);              // longest q-tiles first
    const int b = bid & 3;
    const int h = wid;
    const int q0 = qt * 16;
    const int kswz = (l15 & 7) << 4;              // K read-side XOR (bytes)

    u32* p_sh = p_all[wid];

    bf16x8 qf[4];
    {
        const u16* qrow = Qb + (size_t)(b * S_LEN + q0 + l15) * 512 + h * 128 + g * 8;
        #pragma unroll
        for (int c = 0; c < 4; ++c) qf[c] = *(const bf16x8*)(qrow + c * 32);
    }
    const u16* Kbase = Kb + (size_t)b * S_LEN * 128;
    const u16* Vbase = Vt + (size_t)b * 128 * S_LEN;

    const int klr = lane >> 4, klo = (lane & 15) * 16;  // K: 4 rows (256B) per instr

    auto stage = [&](int buf, int kv0) {
        #pragma unroll
        for (int j = 0; j < 4; ++j) {
            int r0 = wid * 16 + j * 4;
            int row = r0 + klr;
            gload16((const char*)Kbase + (size_t)(kv0 + row) * 256 + (klo ^ ((row & 7) << 4)),
                    &sK[buf][r0 * 128]);
        }
    };

    f32x4 oacc[8] = {};
    float m_r = -1e30f, l_r = 0.f;

    const int nt = (q0 >> 6) + 1;
    stage(0, 0);
    __syncthreads();

    for (int t = 0; t < nt; ++t) {
        const u16* sKc = sK[t & 1];
        if (t + 1 < nt) stage((t + 1) & 1, (t + 1) * 64);
        const int kv0 = t * 64;
        const bool masked = (t == nt - 1);

        // S^T = K * Q^T : sf[st][r] = S[kv0+st*16+g*4+r][q0+l15]
        f32x4 sf[4] = {};
        #pragma unroll
        for (int st = 0; st < 4; ++st) {
            #pragma unroll
            for (int c = 0; c < 4; ++c) {
                bf16x8 kf = *(const bf16x8*)((const char*)sKc +
                                (st * 16 + l15) * 256 + ((c * 64 + g * 16) ^ kswz));
                sf[st] = __builtin_amdgcn_mfma_f32_16x16x32_bf16(kf, qf[c], sf[st], 0, 0, 0);
            }
        }
        float p[16];
        #pragma unroll
        for (int st = 0; st < 4; ++st)
            #pragma unroll
            for (int r = 0; r < 4; ++r) p[st * 4 + r] = sf[st][r];
        if (masked) {
            #pragma unroll
            for (int st = 0; st < 4; ++st)
                #pragma unroll
                for (int r = 0; r < 4; ++r) {
                    int kp = kv0 + st * 16 + g * 4 + r;
                    if (kp > q0 + l15) p[st * 4 + r] = -1e30f;
                }
        }
        float tm = p[0];
        #pragma unroll
        for (int i = 1; i < 16; ++i) tm = fmaxf(tm, p[i]);
        tm = fmaxf(tm, __shfl_xor(tm, 16));
        tm = fmaxf(tm, __shfl_xor(tm, 32));
        float mn = fmaxf(m_r, tm);
        float fscale = exp2f(m_r - mn);
        m_r = mn;
        float rs = 0.f;
        #pragma unroll
        for (int i = 0; i < 16; ++i) { p[i] = exp2f(p[i] - mn); rs += p[i]; }
        rs += __shfl_xor(rs, 16);
        rs += __shfl_xor(rs, 32);
        l_r = l_r * fscale + rs;
        #pragma unroll
        for (int ht = 0; ht < 8; ++ht) oacc[ht] *= fscale;

        // P -> per-wave LDS tile (D-layout -> B-frag layout)
        #pragma unroll
        for (int st = 0; st < 4; ++st) {
            uint2 w;
            w.x = pk2(p[st * 4 + 0], p[st * 4 + 1]);
            w.y = pk2(p[st * 4 + 2], p[st * 4 + 3]);
            *(uint2*)&p_sh[l15 * 36 + st * 8 + g * 2] = w;
        }
        bf16x8 pa0 = *(const bf16x8*)&p_sh[l15 * 36 + g * 4];
        bf16x8 pa1 = *(const bf16x8*)&p_sh[l15 * 36 + 16 + g * 4];

        // O^T += V^T * P^T   (V^T straight from global; L2-hot)
        #pragma unroll
        for (int ht = 0; ht < 8; ++ht) {
            const u16* vrow = Vbase + (size_t)(ht * 16 + l15) * S_LEN + kv0 + g * 8;
            bf16x8 v0 = *(const bf16x8*)vrow;
            bf16x8 v1 = *(const bf16x8*)(vrow + 32);
            oacc[ht] = __builtin_amdgcn_mfma_f32_16x16x32_bf16(v0, pa0, oacc[ht], 0, 0, 0);
            oacc[ht] = __builtin_amdgcn_mfma_f32_16x16x32_bf16(v1, pa1, oacc[ht], 0, 0, 0);
        }
        __syncthreads();
    }

    float inv_l = 1.0f / l_r;
    #pragma unroll
    for (int ht = 0; ht < 8; ++ht) {
        uint2 o;
        o.x = pk2(oacc[ht][0] * inv_l, oacc[ht][1] * inv_l);
        o.y = pk2(oacc[ht][2] * inv_l, oacc[ht][3] * inv_l);
        *(uint2*)&Ob[(size_t)(b * S_LEN + q0 + l15) * 512 + h * 128 + ht * 16 + g * 4] = o;
    }
}

extern "C" void kernel_launch(void* const* d_in, const int* in_sizes, int n_in,
                              void* d_out, int out_size, void* d_ws, size_t ws_size,
                              hipStream_t stream) {
    const float* x         = (const float*)d_in[0];
    const int*   positions = (const int*)d_in[1];
    const float* wq        = (const float*)d_in[2];
    const float* wk        = (const float*)d_in[3];
    const float* wv        = (const float*)d_in[4];
    const float* wo        = (const float*)d_in[5];
    float* out = (float*)d_out;

    // d_out (134.2MB): [0,67.1) = Xb bf16, [67.1,92.3) = P1 (both dead before GEMM2 writes)
    u16*   Xb = (u16*)d_out;
    float* P1 = (float*)((char*)d_out + 67108864);

    char* ws = (char*)d_ws;
    size_t off = 0;
    auto alloc = [&](size_t bytes) { void* p = ws + off; off = (off + bytes + 255) & ~(size_t)255; return p; };
    u16*   Wqkv = (u16*)alloc(768ull * 4096 * 2);
    u16*   WoT  = (u16*)alloc(4096ull * 512 * 2);
    float* P0   = (float*)alloc(8192ull * 768 * 4);
    u16*   Qb   = (u16*)alloc(8192ull * 512 * 2);
    u16*   Kb   = (u16*)alloc(8192ull * 128 * 2);
    u16*   Vt   = (u16*)alloc(4ull * 128 * 2048 * 2);
    u16*   Ob   = (u16*)alloc(8192ull * 512 * 2);

    conv_x_kernel<<<(8192 * 4096) / (4 * 256), 256, 0, stream>>>(x, Xb);
    pack_wqkv_kernel<<<dim3(24, 128), 256, 0, stream>>>(wq, wk, wv, Wqkv);
    pack_wo_kernel<<<dim3(128, 16), 256, 0, stream>>>(wo, WoT);

    // GEMM1 (bf16 Xb): split-K=2, z=0 -> P0, z=1 -> P1
    gemm_pipe<<<dim3(6, 64, 2), 256, 0, stream>>>(Xb, Wqkv, P0, P1, 768, 4096, 2048);

    rope_rms_kernel<<<(8192 * 5) / 4, 256, 0, stream>>>(P0, P1, positions, Qb, Kb);
    vtrans_kernel<<<128, 256, 0, stream>>>(P0, P1, Vt);

    attn_kernel<<<512, 256, 0, stream>>>(Qb, Kb, Vt, Ob);

    // GEMM2 (bf16 Ob)
    gemm_pipe<<<dim3(32, 64, 1), 256, 0, stream>>>(Ob, WoT, out, nullptr, 4096, 512, 512);
}

// Round 14
// 244.382 us; speedup vs baseline: 1.2829x; 1.2829x over previous
//
#include <hip/hip_runtime.h>

typedef unsigned short u16;
typedef unsigned int u32;
typedef __bf16 bf16x8 __attribute__((ext_vector_type(8)));
typedef float f32x4 __attribute__((ext_vector_type(4)));

#define S_LEN 2048

__device__ __forceinline__ u16 f2b(float f) {
    union { float f; unsigned u; } a; a.f = f;
    unsigned u = a.u;
    unsigned r = u + 0x7fffu + ((u >> 16) & 1u);
    return (u16)(r >> 16);
}

__device__ __forceinline__ u32 pk2(float a, float b) {
    return (u32)f2b(a) | ((u32)f2b(b) << 16);
}

__device__ __forceinline__ void gload16(const void* g, void* l) {
    __builtin_amdgcn_global_load_lds(
        (const __attribute__((address_space(1))) unsigned int*)g,
        (__attribute__((address_space(3))) unsigned int*)l,
        16, 0, 0);
}

// ---------- x f32 -> bf16 ----------
__global__ __launch_bounds__(256) void conv_x_kernel(const float* __restrict__ x,
                                                     u16* __restrict__ xb) {
    long i = ((long)blockIdx.x * 256 + threadIdx.x) * 4;
    float4 v = *(const float4*)(x + i);
    ushort4 o;
    o.x = f2b(v.x); o.y = f2b(v.y); o.z = f2b(v.z); o.w = f2b(v.w);
    *(ushort4*)(xb + i) = o;
}

// ---------- transpose-pack wq|wk|wv -> W[768][4096] bf16 (LDS 32x32 tiles) ----------
__global__ __launch_bounds__(256) void pack_wqkv_kernel(const float* __restrict__ wq,
                                                        const float* __restrict__ wk,
                                                        const float* __restrict__ wv,
                                                        u16* __restrict__ W) {
    __shared__ float t[32][33];
    const int n0 = blockIdx.x * 32, k0 = blockIdx.y * 32;
    const int tid = threadIdx.x;
    const int cc = tid & 31, rr = tid >> 5;
    #pragma unroll
    for (int i = 0; i < 4; ++i) {
        int k = k0 + rr + i * 8, n = n0 + cc;
        float v;
        if (n < 512)      v = wq[(size_t)k * 512 + n];
        else if (n < 640) v = wk[(size_t)k * 128 + (n - 512)];
        else              v = wv[(size_t)k * 128 + (n - 640)];
        t[rr + i * 8][cc] = v;
    }
    __syncthreads();
    #pragma unroll
    for (int i = 0; i < 4; ++i) {
        int nn = rr + i * 8, kk = cc;
        W[(size_t)(n0 + nn) * 4096 + k0 + kk] = f2b(t[kk][nn]);
    }
}

// ---------- transpose-pack wo[512][4096] -> WoT[4096][512] bf16 ----------
__global__ __launch_bounds__(256) void pack_wo_kernel(const float* __restrict__ wo,
                                                      u16* __restrict__ W) {
    __shared__ float t[32][33];
    const int n0 = blockIdx.x * 32, k0 = blockIdx.y * 32;
    const int tid = threadIdx.x;
    const int cc = tid & 31, rr = tid >> 5;
    #pragma unroll
    for (int i = 0; i < 4; ++i)
        t[rr + i * 8][cc] = wo[(size_t)(k0 + rr + i * 8) * 4096 + n0 + cc];
    __syncthreads();
    #pragma unroll
    for (int i = 0; i < 4; ++i)
        W[(size_t)(n0 + rr + i * 8) * 512 + k0 + cc] = f2b(t[cc][rr + i * 8]);
}

// ---------- GEMM: C = A(MxK,bf16) * B^T(NxK,bf16), counted-vmcnt 3-deep ring ----------
// Per iter: wait vmcnt(4) (stage t done; only stage t+1 newer), raw barrier, issue
// stage t+2 (overwrites buf t-1, whose reads drained before the barrier), MFMA on t.
// Loads live 2 full iterations; vmcnt->0 only at the last iter. LDS XOR-swizzled
// via pre-swizzled global source (conflicts=0, r7). XCD remap: xcd=lid%8 owns a
// contiguous bm chunk. Requires gridDim.y % 8 == 0, kBase/32 >= 2.
__global__ __launch_bounds__(256) void gemm_pipe(const u16* __restrict__ A,
                                                 const u16* __restrict__ B,
                                                 float* __restrict__ C0,
                                                 float* __restrict__ C1,
                                                 int N, int K, int kBase) {
    __shared__ __align__(16) u16 sA[3][128 * 32];
    __shared__ __align__(16) u16 sB[3][128 * 32];
    const int tid = threadIdx.x;
    const int lane = tid & 63, wid = tid >> 6;
    const int wr = wid >> 1, wc = wid & 1;
    const int l15 = lane & 15, g = lane >> 4;
    const int srow = lane >> 2;
    const int swzc = ((lane & 3) * 8) ^ (((lane >> 3) & 3) << 3);
    const int rswz = ((l15 >> 1) & 3) << 3;

    const u32 lid = blockIdx.x + gridDim.x * (blockIdx.y + gridDim.y * blockIdx.z);
    const u32 xcd = lid & 7, slot = lid >> 3;
    const u32 per = gridDim.x * gridDim.z;
    const u32 bml = slot / per;
    const u32 rmd = slot - bml * per;
    const int bn = rmd % gridDim.x;
    const int z  = rmd / gridDim.x;
    const int bm = xcd * (gridDim.y >> 3) + bml;

    float* C = z ? C1 : C0;
    const int k0 = z * kBase;
    const int nt = kBase / 32;

    const int ch0 = wid * 2, ch1 = wid * 2 + 1;
    const int r0 = ch0 * 16 + srow, r1 = ch1 * 16 + srow;

    auto stage = [&](int buf, int kt) {
        gload16(&A[(size_t)(bm * 128 + r0) * K + kt + swzc], &sA[buf][ch0 * 512]);
        gload16(&A[(size_t)(bm * 128 + r1) * K + kt + swzc], &sA[buf][ch1 * 512]);
        gload16(&B[(size_t)(bn * 128 + r0) * K + kt + swzc], &sB[buf][ch0 * 512]);
        gload16(&B[(size_t)(bn * 128 + r1) * K + kt + swzc], &sB[buf][ch1 * 512]);
    };

    f32x4 acc[4][4] = {};

    stage(0, k0);
    stage(1, k0 + 32);

    for (int t = 0; t < nt; ++t) {
        if (t + 1 < nt) asm volatile("s_waitcnt vmcnt(4)" ::: "memory");
        else            asm volatile("s_waitcnt vmcnt(0)" ::: "memory");
        __builtin_amdgcn_s_barrier();
        __builtin_amdgcn_sched_barrier(0);
        if (t + 2 < nt) stage((t + 2) % 3, k0 + (t + 2) * 32);
        const int cur = t % 3;
        bf16x8 af[4], bfr[4];
        #pragma unroll
        for (int m = 0; m < 4; ++m)
            af[m] = *(const bf16x8*)&sA[cur][(wr * 64 + m * 16 + l15) * 32 + (g * 8 ^ rswz)];
        #pragma unroll
        for (int n = 0; n < 4; ++n)
            bfr[n] = *(const bf16x8*)&sB[cur][(wc * 64 + n * 16 + l15) * 32 + (g * 8 ^ rswz)];
        #pragma unroll
        for (int m = 0; m < 4; ++m)
            #pragma unroll
            for (int n = 0; n < 4; ++n)
                acc[m][n] = __builtin_amdgcn_mfma_f32_16x16x32_bf16(af[m], bfr[n], acc[m][n], 0, 0, 0);
    }

    #pragma unroll
    for (int m = 0; m < 4; ++m) {
        int row = bm * 128 + wr * 64 + m * 16 + g * 4;
        #pragma unroll
        for (int n = 0; n < 4; ++n) {
            int col = bn * 128 + wc * 64 + n * 16 + l15;
            #pragma unroll
            for (int rr = 0; rr < 4; ++rr)
                C[(size_t)(row + rr) * N + col] = acc[m][n][rr];
        }
    }
}

// ---------- RoPE + RMSNorm + scales: (P0+P1)(f32) -> Qb/Kb (bf16) ----------
__global__ __launch_bounds__(256) void rope_rms_kernel(const float* __restrict__ P0,
                                                       const float* __restrict__ P1,
                                                       const int* __restrict__ positions,
                                                       u16* __restrict__ Qb,
                                                       u16* __restrict__ Kb) {
    const int w = blockIdx.x * 4 + (threadIdx.x >> 6);
    const int lane = threadIdx.x & 63;
    const int row = w / 5, head = w - row * 5;
    const int s = row & (S_LEN - 1);

    float pos = (float)positions[s];
    float ex = (float)(2 * lane) * (1.0f / 128.0f);
    float inv_freq = __expf(-ex * 13.122363377404328f);   // ln(500000)
    float ang = pos * inv_freq;
    float c, sn;
    __sincosf(ang, &sn, &c);

    size_t off = (size_t)row * 768 + head * 128 + 2 * lane;
    float2 va = *(const float2*)&P0[off];
    float2 vb = *(const float2*)&P1[off];
    float x0 = va.x + vb.x, x1 = va.y + vb.y;
    float o0 = x0 * c - x1 * sn;
    float o1 = x0 * sn + x1 * c;

    float ss = o0 * o0 + o1 * o1;
    #pragma unroll
    for (int m = 1; m < 64; m <<= 1) ss += __shfl_xor(ss, m, 64);
    float rms = rsqrtf(ss * (1.0f / 128.0f) + 1e-6f);

    if (head < 4) {
        float ascale = logf(floorf((pos + 1.0f) * (1.0f / 8192.0f)) + 1.0f) * 0.1f + 1.0f;
        // fold 1/sqrt(128) * (1/ln2) so attention uses exp2
        float mult = rms * ascale * 0.12751743f;
        *(u32*)&Qb[(size_t)row * 512 + head * 128 + 2 * lane] = pk2(o0 * mult, o1 * mult);
    } else {
        *(u32*)&Kb[(size_t)row * 128 + 2 * lane] = pk2(o0 * rms, o1 * rms);
    }
}

// ---------- V slice of (P0+P1) -> Vt[b][d][s] bf16 (LDS tile transpose) ----------
__global__ __launch_bounds__(256) void vtrans_kernel(const float* __restrict__ P0,
                                                     const float* __restrict__ P1,
                                                     u16* __restrict__ Vt) {
    __shared__ u16 tile[128][72];
    const int bi = blockIdx.x >> 5, st = blockIdx.x & 31;
    const int s0 = st * 64;
    const int tid = threadIdx.x;
    #pragma unroll
    for (int i = 0; i < 8; ++i) {
        int idx = i * 256 + tid;
        int r = idx >> 5, c4 = idx & 31;
        size_t off = (size_t)(bi * S_LEN + s0 + r) * 768 + 640 + c4 * 4;
        float4 a = *(const float4*)&P0[off];
        float4 b = *(const float4*)&P1[off];
        tile[c4 * 4 + 0][r] = f2b(a.x + b.x);
        tile[c4 * 4 + 1][r] = f2b(a.y + b.y);
        tile[c4 * 4 + 2][r] = f2b(a.z + b.z);
        tile[c4 * 4 + 3][r] = f2b(a.w + b.w);
    }
    __syncthreads();
    #pragma unroll
    for (int i = 0; i < 4; ++i) {
        int idx = i * 256 + tid;
        int d = idx >> 3, sl = idx & 7;
        bf16x8 v = *(const bf16x8*)&tile[d][sl * 8];
        *(bf16x8*)&Vt[((size_t)bi * 128 + d) * S_LEN + s0 + sl * 8] = v;
    }
}

// ---------- flash attention (causal, GQA 4:1) ----------
// block = (b, q-tile of 16); 4 waves = 4 heads SHARING LDS-staged K/V (dbuf, swizzled).
__global__ __launch_bounds__(256) void attn_kernel(const u16* __restrict__ Qb,
                                                   const u16* __restrict__ Kb,
                                                   const u16* __restrict__ Vt,
                                                   u16* __restrict__ Ob) {
    __shared__ __align__(16) u16 sK[2][64 * 128];
    __shared__ __align__(16) u16 sV[2][128 * 64];
    __shared__ __align__(16) u32 p_all[4][16 * 36];
    const int tid = threadIdx.x;
    const int lane = tid & 63, wid = tid >> 6;    // wid = head
    const int l15 = lane & 15, g = lane >> 4;
    const int bid = blockIdx.x;
    const int qt = 127 - (bid >> 2);              // longest q-tiles first
    const int b = bid & 3;
    const int h = wid;
    const int q0 = qt * 16;
    const int kswz = (l15 & 7) << 4;              // read-side XOR (bytes)

    u32* p_sh = p_all[wid];

    bf16x8 qf[4];
    {
        const u16* qrow = Qb + (size_t)(b * S_LEN + q0 + l15) * 512 + h * 128 + g * 8;
        #pragma unroll
        for (int c = 0; c < 4; ++c) qf[c] = *(const bf16x8*)(qrow + c * 32);
    }
    const u16* Kbase = Kb + (size_t)b * S_LEN * 128;
    const u16* Vbase = Vt + (size_t)b * 128 * S_LEN;

    const int klr = lane >> 4, klo = (lane & 15) * 16;
    const int vlr = lane >> 3, vlo = (lane & 7) * 16;

    auto stage = [&](int buf, int kv0) {
        #pragma unroll
        for (int j = 0; j < 4; ++j) {
            int r0 = wid * 16 + j * 4;
            int row = r0 + klr;
            gload16((const char*)Kbase + (size_t)(kv0 + row) * 256 + (klo ^ ((row & 7) << 4)),
                    &sK[buf][r0 * 128]);
        }
        #pragma unroll
        for (int j = 0; j < 4; ++j) {
            int r0 = wid * 32 + j * 8;
            int row = r0 + vlr;
            gload16((const char*)Vbase + (size_t)row * (S_LEN * 2) + (size_t)kv0 * 2 + (vlo ^ ((row & 7) << 4)),
                    &sV[buf][r0 * 64]);
        }
    };

    f32x4 oacc[8] = {};
    float m_r = -1e30f, l_r = 0.f;

    const int nt = (q0 >> 6) + 1;
    stage(0, 0);
    __syncthreads();

    for (int t = 0; t < nt; ++t) {
        const u16* sKc = sK[t & 1];
        const u16* sVc = sV[t & 1];
        if (t + 1 < nt) stage((t + 1) & 1, (t + 1) * 64);
        const int kv0 = t * 64;
        const bool masked = (t == nt - 1);

        f32x4 sf[4] = {};
        #pragma unroll
        for (int st = 0; st < 4; ++st) {
            #pragma unroll
            for (int c = 0; c < 4; ++c) {
                bf16x8 kf = *(const bf16x8*)((const char*)sKc +
                                (st * 16 + l15) * 256 + ((c * 64 + g * 16) ^ kswz));
                sf[st] = __builtin_amdgcn_mfma_f32_16x16x32_bf16(kf, qf[c], sf[st], 0, 0, 0);
            }
        }
        float p[16];
        #pragma unroll
        for (int st = 0; st < 4; ++st)
            #pragma unroll
            for (int r = 0; r < 4; ++r) p[st * 4 + r] = sf[st][r];
        if (masked) {
            #pragma unroll
            for (int st = 0; st < 4; ++st)
                #pragma unroll
                for (int r = 0; r < 4; ++r) {
                    int kp = kv0 + st * 16 + g * 4 + r;
                    if (kp > q0 + l15) p[st * 4 + r] = -1e30f;
                }
        }
        float tm = p[0];
        #pragma unroll
        for (int i = 1; i < 16; ++i) tm = fmaxf(tm, p[i]);
        tm = fmaxf(tm, __shfl_xor(tm, 16));
        tm = fmaxf(tm, __shfl_xor(tm, 32));
        float mn = fmaxf(m_r, tm);
        float fscale = exp2f(m_r - mn);
        m_r = mn;
        float rs = 0.f;
        #pragma unroll
        for (int i = 0; i < 16; ++i) { p[i] = exp2f(p[i] - mn); rs += p[i]; }
        rs += __shfl_xor(rs, 16);
        rs += __shfl_xor(rs, 32);
        l_r = l_r * fscale + rs;
        #pragma unroll
        for (int ht = 0; ht < 8; ++ht) oacc[ht] *= fscale;

        #pragma unroll
        for (int st = 0; st < 4; ++st) {
            uint2 w;
            w.x = pk2(p[st * 4 + 0], p[st * 4 + 1]);
            w.y = pk2(p[st * 4 + 2], p[st * 4 + 3]);
            *(uint2*)&p_sh[l15 * 36 + st * 8 + g * 2] = w;
        }
        bf16x8 pa0 = *(const bf16x8*)&p_sh[l15 * 36 + g * 4];
        bf16x8 pa1 = *(const bf16x8*)&p_sh[l15 * 36 + 16 + g * 4];

        #pragma unroll
        for (int ht = 0; ht < 8; ++ht) {
            bf16x8 v0 = *(const bf16x8*)((const char*)sVc +
                            (ht * 16 + l15) * 128 + ((g * 16) ^ kswz));
            bf16x8 v1 = *(const bf16x8*)((const char*)sVc +
                            (ht * 16 + l15) * 128 + ((64 + g * 16) ^ kswz));
            oacc[ht] = __builtin_amdgcn_mfma_f32_16x16x32_bf16(v0, pa0, oacc[ht], 0, 0, 0);
            oacc[ht] = __builtin_amdgcn_mfma_f32_16x16x32_bf16(v1, pa1, oacc[ht], 0, 0, 0);
        }
        __syncthreads();
    }

    float inv_l = 1.0f / l_r;
    #pragma unroll
    for (int ht = 0; ht < 8; ++ht) {
        uint2 o;
        o.x = pk2(oacc[ht][0] * inv_l, oacc[ht][1] * inv_l);
        o.y = pk2(oacc[ht][2] * inv_l, oacc[ht][3] * inv_l);
        *(uint2*)&Ob[(size_t)(b * S_LEN + q0 + l15) * 512 + h * 128 + ht * 16 + g * 4] = o;
    }
}

extern "C" void kernel_launch(void* const* d_in, const int* in_sizes, int n_in,
                              void* d_out, int out_size, void* d_ws, size_t ws_size,
                              hipStream_t stream) {
    const float* x         = (const float*)d_in[0];
    const int*   positions = (const int*)d_in[1];
    const float* wq        = (const float*)d_in[2];
    const float* wk        = (const float*)d_in[3];
    const float* wv        = (const float*)d_in[4];
    const float* wo        = (const float*)d_in[5];
    float* out = (float*)d_out;

    // d_out (134.2MB): [0,67.1) = Xb bf16, [67.1,92.3) = P1 (both dead before GEMM2 writes)
    u16*   Xb = (u16*)d_out;
    float* P1 = (float*)((char*)d_out + 67108864);

    char* ws = (char*)d_ws;
    size_t off = 0;
    auto alloc = [&](size_t bytes) { void* p = ws + off; off = (off + bytes + 255) & ~(size_t)255; return p; };
    u16*   Wqkv = (u16*)alloc(768ull * 4096 * 2);
    u16*   WoT  = (u16*)alloc(4096ull * 512 * 2);
    float* P0   = (float*)alloc(8192ull * 768 * 4);
    u16*   Qb   = (u16*)alloc(8192ull * 512 * 2);
    u16*   Kb   = (u16*)alloc(8192ull * 128 * 2);
    u16*   Vt   = (u16*)alloc(4ull * 128 * 2048 * 2);
    u16*   Ob   = (u16*)alloc(8192ull * 512 * 2);

    conv_x_kernel<<<(8192 * 4096) / (4 * 256), 256, 0, stream>>>(x, Xb);
    pack_wqkv_kernel<<<dim3(24, 128), 256, 0, stream>>>(wq, wk, wv, Wqkv);
    pack_wo_kernel<<<dim3(128, 16), 256, 0, stream>>>(wo, WoT);

    // GEMM1 (bf16 Xb): split-K=2, z=0 -> P0, z=1 -> P1
    gemm_pipe<<<dim3(6, 64, 2), 256, 0, stream>>>(Xb, Wqkv, P0, P1, 768, 4096, 2048);

    rope_rms_kernel<<<(8192 * 5) / 4, 256, 0, stream>>>(P0, P1, positions, Qb, Kb);
    vtrans_kernel<<<128, 256, 0, stream>>>(P0, P1, Vt);

    attn_kernel<<<512, 256, 0, stream>>>(Qb, Kb, Vt, Ob);

    // GEMM2 (bf16 Ob)
    gemm_pipe<<<dim3(32, 64, 1), 256, 0, stream>>>(Ob, WoT, out, nullptr, 4096, 512, 512);
}

// Round 15
// 243.135 us; speedup vs baseline: 1.2895x; 1.0051x over previous
//
#include <hip/hip_runtime.h>

typedef unsigned short u16;
typedef unsigned int u32;
typedef __bf16 bf16x8 __attribute__((ext_vector_type(8)));
typedef float f32x4 __attribute__((ext_vector_type(4)));

#define S_LEN 2048

__device__ __forceinline__ u16 f2b(float f) {
    union { float f; unsigned u; } a; a.f = f;
    unsigned u = a.u;
    unsigned r = u + 0x7fffu + ((u >> 16) & 1u);
    return (u16)(r >> 16);
}

__device__ __forceinline__ float b2f(u32 h) {
    union { u32 u; float f; } c; c.u = h << 16; return c.f;
}

__device__ __forceinline__ u32 pk2(float a, float b) {
    return (u32)f2b(a) | ((u32)f2b(b) << 16);
}

__device__ __forceinline__ void gload16(const void* g, void* l) {
    __builtin_amdgcn_global_load_lds(
        (const __attribute__((address_space(1))) unsigned int*)g,
        (__attribute__((address_space(3))) unsigned int*)l,
        16, 0, 0);
}

// ---------- x f32 -> bf16 ----------
__global__ __launch_bounds__(256) void conv_x_kernel(const float* __restrict__ x,
                                                     u16* __restrict__ xb) {
    long i = ((long)blockIdx.x * 256 + threadIdx.x) * 4;
    float4 v = *(const float4*)(x + i);
    ushort4 o;
    o.x = f2b(v.x); o.y = f2b(v.y); o.z = f2b(v.z); o.w = f2b(v.w);
    *(ushort4*)(xb + i) = o;
}

// ---------- transpose-pack wq|wk|wv -> W[768][4096] bf16 (LDS 32x32 tiles) ----------
__global__ __launch_bounds__(256) void pack_wqkv_kernel(const float* __restrict__ wq,
                                                        const float* __restrict__ wk,
                                                        const float* __restrict__ wv,
                                                        u16* __restrict__ W) {
    __shared__ float t[32][33];
    const int n0 = blockIdx.x * 32, k0 = blockIdx.y * 32;
    const int tid = threadIdx.x;
    const int cc = tid & 31, rr = tid >> 5;
    #pragma unroll
    for (int i = 0; i < 4; ++i) {
        int k = k0 + rr + i * 8, n = n0 + cc;
        float v;
        if (n < 512)      v = wq[(size_t)k * 512 + n];
        else if (n < 640) v = wk[(size_t)k * 128 + (n - 512)];
        else              v = wv[(size_t)k * 128 + (n - 640)];
        t[rr + i * 8][cc] = v;
    }
    __syncthreads();
    #pragma unroll
    for (int i = 0; i < 4; ++i) {
        int nn = rr + i * 8, kk = cc;
        W[(size_t)(n0 + nn) * 4096 + k0 + kk] = f2b(t[kk][nn]);
    }
}

// ---------- transpose-pack wo[512][4096] -> WoT[4096][512] bf16 ----------
__global__ __launch_bounds__(256) void pack_wo_kernel(const float* __restrict__ wo,
                                                      u16* __restrict__ W) {
    __shared__ float t[32][33];
    const int n0 = blockIdx.x * 32, k0 = blockIdx.y * 32;
    const int tid = threadIdx.x;
    const int cc = tid & 31, rr = tid >> 5;
    #pragma unroll
    for (int i = 0; i < 4; ++i)
        t[rr + i * 8][cc] = wo[(size_t)(k0 + rr + i * 8) * 4096 + n0 + cc];
    __syncthreads();
    #pragma unroll
    for (int i = 0; i < 4; ++i)
        W[(size_t)(n0 + rr + i * 8) * 512 + k0 + cc] = f2b(t[cc][rr + i * 8]);
}

// ---------- GEMM: C = A(MxK,bf16) * B^T(NxK,bf16), counted-vmcnt 3-deep ring (r10) ----------
// OBF=1: write C as bf16 (split-K partials); OBF=0: write f32.
__global__ __launch_bounds__(256) void gemm_pipe_bf(const u16* __restrict__ A,
                                                    const u16* __restrict__ B,
                                                    u16* __restrict__ C0,
                                                    u16* __restrict__ C1,
                                                    int N, int K, int kBase) {
    __shared__ __align__(16) u16 sA[3][128 * 32];
    __shared__ __align__(16) u16 sB[3][128 * 32];
    const int tid = threadIdx.x;
    const int lane = tid & 63, wid = tid >> 6;
    const int wr = wid >> 1, wc = wid & 1;
    const int l15 = lane & 15, g = lane >> 4;
    const int srow = lane >> 2;
    const int swzc = ((lane & 3) * 8) ^ (((lane >> 3) & 3) << 3);
    const int rswz = ((l15 >> 1) & 3) << 3;

    const u32 lid = blockIdx.x + gridDim.x * (blockIdx.y + gridDim.y * blockIdx.z);
    const u32 xcd = lid & 7, slot = lid >> 3;
    const u32 per = gridDim.x * gridDim.z;
    const u32 bml = slot / per;
    const u32 rmd = slot - bml * per;
    const int bn = rmd % gridDim.x;
    const int z  = rmd / gridDim.x;
    const int bm = xcd * (gridDim.y >> 3) + bml;

    u16* C = z ? C1 : C0;
    const int k0 = z * kBase;
    const int nt = kBase / 32;

    const int ch0 = wid * 2, ch1 = wid * 2 + 1;
    const int r0 = ch0 * 16 + srow, r1 = ch1 * 16 + srow;

    auto stage = [&](int buf, int kt) {
        gload16(&A[(size_t)(bm * 128 + r0) * K + kt + swzc], &sA[buf][ch0 * 512]);
        gload16(&A[(size_t)(bm * 128 + r1) * K + kt + swzc], &sA[buf][ch1 * 512]);
        gload16(&B[(size_t)(bn * 128 + r0) * K + kt + swzc], &sB[buf][ch0 * 512]);
        gload16(&B[(size_t)(bn * 128 + r1) * K + kt + swzc], &sB[buf][ch1 * 512]);
    };

    f32x4 acc[4][4] = {};

    stage(0, k0);
    stage(1, k0 + 32);

    for (int t = 0; t < nt; ++t) {
        if (t + 1 < nt) asm volatile("s_waitcnt vmcnt(4)" ::: "memory");
        else            asm volatile("s_waitcnt vmcnt(0)" ::: "memory");
        __builtin_amdgcn_s_barrier();
        __builtin_amdgcn_sched_barrier(0);
        if (t + 2 < nt) stage((t + 2) % 3, k0 + (t + 2) * 32);
        const int cur = t % 3;
        bf16x8 af[4], bfr[4];
        #pragma unroll
        for (int m = 0; m < 4; ++m)
            af[m] = *(const bf16x8*)&sA[cur][(wr * 64 + m * 16 + l15) * 32 + (g * 8 ^ rswz)];
        #pragma unroll
        for (int n = 0; n < 4; ++n)
            bfr[n] = *(const bf16x8*)&sB[cur][(wc * 64 + n * 16 + l15) * 32 + (g * 8 ^ rswz)];
        #pragma unroll
        for (int m = 0; m < 4; ++m)
            #pragma unroll
            for (int n = 0; n < 4; ++n)
                acc[m][n] = __builtin_amdgcn_mfma_f32_16x16x32_bf16(af[m], bfr[n], acc[m][n], 0, 0, 0);
    }

    #pragma unroll
    for (int m = 0; m < 4; ++m) {
        int row = bm * 128 + wr * 64 + m * 16 + g * 4;
        #pragma unroll
        for (int n = 0; n < 4; ++n) {
            int col = bn * 128 + wc * 64 + n * 16 + l15;
            #pragma unroll
            for (int rr = 0; rr < 4; ++rr)
                C[(size_t)(row + rr) * N + col] = f2b(acc[m][n][rr]);
        }
    }
}

__global__ __launch_bounds__(256) void gemm_pipe(const u16* __restrict__ A,
                                                 const u16* __restrict__ B,
                                                 float* __restrict__ C,
                                                 int N, int K) {
    __shared__ __align__(16) u16 sA[3][128 * 32];
    __shared__ __align__(16) u16 sB[3][128 * 32];
    const int tid = threadIdx.x;
    const int lane = tid & 63, wid = tid >> 6;
    const int wr = wid >> 1, wc = wid & 1;
    const int l15 = lane & 15, g = lane >> 4;
    const int srow = lane >> 2;
    const int swzc = ((lane & 3) * 8) ^ (((lane >> 3) & 3) << 3);
    const int rswz = ((l15 >> 1) & 3) << 3;

    const u32 lid = blockIdx.x + gridDim.x * blockIdx.y;
    const u32 xcd = lid & 7, slot = lid >> 3;
    const u32 per = gridDim.x;
    const u32 bml = slot / per;
    const int bn = slot - bml * per;
    const int bm = xcd * (gridDim.y >> 3) + bml;

    const int nt = K / 32;
    const int ch0 = wid * 2, ch1 = wid * 2 + 1;
    const int r0 = ch0 * 16 + srow, r1 = ch1 * 16 + srow;

    auto stage = [&](int buf, int kt) {
        gload16(&A[(size_t)(bm * 128 + r0) * K + kt + swzc], &sA[buf][ch0 * 512]);
        gload16(&A[(size_t)(bm * 128 + r1) * K + kt + swzc], &sA[buf][ch1 * 512]);
        gload16(&B[(size_t)(bn * 128 + r0) * K + kt + swzc], &sB[buf][ch0 * 512]);
        gload16(&B[(size_t)(bn * 128 + r1) * K + kt + swzc], &sB[buf][ch1 * 512]);
    };

    f32x4 acc[4][4] = {};

    stage(0, 0);
    stage(1, 32);

    for (int t = 0; t < nt; ++t) {
        if (t + 1 < nt) asm volatile("s_waitcnt vmcnt(4)" ::: "memory");
        else            asm volatile("s_waitcnt vmcnt(0)" ::: "memory");
        __builtin_amdgcn_s_barrier();
        __builtin_amdgcn_sched_barrier(0);
        if (t + 2 < nt) stage((t + 2) % 3, (t + 2) * 32);
        const int cur = t % 3;
        bf16x8 af[4], bfr[4];
        #pragma unroll
        for (int m = 0; m < 4; ++m)
            af[m] = *(const bf16x8*)&sA[cur][(wr * 64 + m * 16 + l15) * 32 + (g * 8 ^ rswz)];
        #pragma unroll
        for (int n = 0; n < 4; ++n)
            bfr[n] = *(const bf16x8*)&sB[cur][(wc * 64 + n * 16 + l15) * 32 + (g * 8 ^ rswz)];
        #pragma unroll
        for (int m = 0; m < 4; ++m)
            #pragma unroll
            for (int n = 0; n < 4; ++n)
                acc[m][n] = __builtin_amdgcn_mfma_f32_16x16x32_bf16(af[m], bfr[n], acc[m][n], 0, 0, 0);
    }

    #pragma unroll
    for (int m = 0; m < 4; ++m) {
        int row = bm * 128 + wr * 64 + m * 16 + g * 4;
        #pragma unroll
        for (int n = 0; n < 4; ++n) {
            int col = bn * 128 + wc * 64 + n * 16 + l15;
            #pragma unroll
            for (int rr = 0; rr < 4; ++rr)
                C[(size_t)(row + rr) * N + col] = acc[m][n][rr];
        }
    }
}

// ---------- RoPE + RMSNorm + scales: (P0+P1)(bf16) -> Qb/Kb (bf16) ----------
__global__ __launch_bounds__(256) void rope_rms_kernel(const u16* __restrict__ P0,
                                                       const u16* __restrict__ P1,
                                                       const int* __restrict__ positions,
                                                       u16* __restrict__ Qb,
                                                       u16* __restrict__ Kb) {
    const int w = blockIdx.x * 4 + (threadIdx.x >> 6);
    const int lane = threadIdx.x & 63;
    const int row = w / 5, head = w - row * 5;
    const int s = row & (S_LEN - 1);

    float pos = (float)positions[s];
    float ex = (float)(2 * lane) * (1.0f / 128.0f);
    float inv_freq = __expf(-ex * 13.122363377404328f);   // ln(500000)
    float ang = pos * inv_freq;
    float c, sn;
    __sincosf(ang, &sn, &c);

    size_t off = (size_t)row * 768 + head * 128 + 2 * lane;
    u32 pa = *(const u32*)&P0[off];
    u32 pb = *(const u32*)&P1[off];
    float x0 = b2f(pa & 0xffffu) + b2f(pb & 0xffffu);
    float x1 = b2f(pa >> 16)     + b2f(pb >> 16);
    float o0 = x0 * c - x1 * sn;
    float o1 = x0 * sn + x1 * c;

    float ss = o0 * o0 + o1 * o1;
    #pragma unroll
    for (int m = 1; m < 64; m <<= 1) ss += __shfl_xor(ss, m, 64);
    float rms = rsqrtf(ss * (1.0f / 128.0f) + 1e-6f);

    if (head < 4) {
        float ascale = logf(floorf((pos + 1.0f) * (1.0f / 8192.0f)) + 1.0f) * 0.1f + 1.0f;
        // fold 1/sqrt(128) * (1/ln2) so attention uses exp2
        float mult = rms * ascale * 0.12751743f;
        *(u32*)&Qb[(size_t)row * 512 + head * 128 + 2 * lane] = pk2(o0 * mult, o1 * mult);
    } else {
        *(u32*)&Kb[(size_t)row * 128 + 2 * lane] = pk2(o0 * rms, o1 * rms);
    }
}

// ---------- V slice of (P0+P1)(bf16) -> Vt[b][d][s] bf16 (LDS tile transpose) ----------
__global__ __launch_bounds__(256) void vtrans_kernel(const u16* __restrict__ P0,
                                                     const u16* __restrict__ P1,
                                                     u16* __restrict__ Vt) {
    __shared__ u16 tile[128][72];
    const int bi = blockIdx.x >> 5, st = blockIdx.x & 31;
    const int s0 = st * 64;
    const int tid = threadIdx.x;
    #pragma unroll
    for (int i = 0; i < 8; ++i) {
        int idx = i * 256 + tid;
        int r = idx >> 5, c4 = idx & 31;
        size_t off = (size_t)(bi * S_LEN + s0 + r) * 768 + 640 + c4 * 4;
        uint2 a = *(const uint2*)&P0[off];
        uint2 b = *(const uint2*)&P1[off];
        tile[c4 * 4 + 0][r] = f2b(b2f(a.x & 0xffffu) + b2f(b.x & 0xffffu));
        tile[c4 * 4 + 1][r] = f2b(b2f(a.x >> 16)     + b2f(b.x >> 16));
        tile[c4 * 4 + 2][r] = f2b(b2f(a.y & 0xffffu) + b2f(b.y & 0xffffu));
        tile[c4 * 4 + 3][r] = f2b(b2f(a.y >> 16)     + b2f(b.y >> 16));
    }
    __syncthreads();
    #pragma unroll
    for (int i = 0; i < 4; ++i) {
        int idx = i * 256 + tid;
        int d = idx >> 3, sl = idx & 7;
        bf16x8 v = *(const bf16x8*)&tile[d][sl * 8];
        *(bf16x8*)&Vt[((size_t)bi * 128 + d) * S_LEN + s0 + sl * 8] = v;
    }
}

// ---------- flash attention (causal, GQA 4:1) ----------
// block = (b, q-tile of 16); 4 waves = 4 heads SHARING LDS-staged K/V (dbuf, swizzled).
__global__ __launch_bounds__(256) void attn_kernel(const u16* __restrict__ Qb,
                                                   const u16* __restrict__ Kb,
                                                   const u16* __restrict__ Vt,
                                                   u16* __restrict__ Ob) {
    __shared__ __align__(16) u16 sK[2][64 * 128];
    __shared__ __align__(16) u16 sV[2][128 * 64];
    __shared__ __align__(16) u32 p_all[4][16 * 36];
    const int tid = threadIdx.x;
    const int lane = tid & 63, wid = tid >> 6;    // wid = head
    const int l15 = lane & 15, g = lane >> 4;
    const int bid = blockIdx.x;
    const int qt = 127 - (bid >> 2);              // longest q-tiles first
    const int b = bid & 3;
    const int h = wid;
    const int q0 = qt * 16;
    const int kswz = (l15 & 7) << 4;              // read-side XOR (bytes)

    u32* p_sh = p_all[wid];

    bf16x8 qf[4];
    {
        const u16* qrow = Qb + (size_t)(b * S_LEN + q0 + l15) * 512 + h * 128 + g * 8;
        #pragma unroll
        for (int c = 0; c < 4; ++c) qf[c] = *(const bf16x8*)(qrow + c * 32);
    }
    const u16* Kbase = Kb + (size_t)b * S_LEN * 128;
    const u16* Vbase = Vt + (size_t)b * 128 * S_LEN;

    const int klr = lane >> 4, klo = (lane & 15) * 16;
    const int vlr = lane >> 3, vlo = (lane & 7) * 16;

    auto stage = [&](int buf, int kv0) {
        #pragma unroll
        for (int j = 0; j < 4; ++j) {
            int r0 = wid * 16 + j * 4;
            int row = r0 + klr;
            gload16((const char*)Kbase + (size_t)(kv0 + row) * 256 + (klo ^ ((row & 7) << 4)),
                    &sK[buf][r0 * 128]);
        }
        #pragma unroll
        for (int j = 0; j < 4; ++j) {
            int r0 = wid * 32 + j * 8;
            int row = r0 + vlr;
            gload16((const char*)Vbase + (size_t)row * (S_LEN * 2) + (size_t)kv0 * 2 + (vlo ^ ((row & 7) << 4)),
                    &sV[buf][r0 * 64]);
        }
    };

    f32x4 oacc[8] = {};
    float m_r = -1e30f, l_r = 0.f;

    const int nt = (q0 >> 6) + 1;
    stage(0, 0);
    __syncthreads();

    for (int t = 0; t < nt; ++t) {
        const u16* sKc = sK[t & 1];
        const u16* sVc = sV[t & 1];
        if (t + 1 < nt) stage((t + 1) & 1, (t + 1) * 64);
        const int kv0 = t * 64;
        const bool masked = (t == nt - 1);

        f32x4 sf[4] = {};
        #pragma unroll
        for (int st = 0; st < 4; ++st) {
            #pragma unroll
            for (int c = 0; c < 4; ++c) {
                bf16x8 kf = *(const bf16x8*)((const char*)sKc +
                                (st * 16 + l15) * 256 + ((c * 64 + g * 16) ^ kswz));
                sf[st] = __builtin_amdgcn_mfma_f32_16x16x32_bf16(kf, qf[c], sf[st], 0, 0, 0);
            }
        }
        float p[16];
        #pragma unroll
        for (int st = 0; st < 4; ++st)
            #pragma unroll
            for (int r = 0; r < 4; ++r) p[st * 4 + r] = sf[st][r];
        if (masked) {
            #pragma unroll
            for (int st = 0; st < 4; ++st)
                #pragma unroll
                for (int r = 0; r < 4; ++r) {
                    int kp = kv0 + st * 16 + g * 4 + r;
                    if (kp > q0 + l15) p[st * 4 + r] = -1e30f;
                }
        }
        float tm = p[0];
        #pragma unroll
        for (int i = 1; i < 16; ++i) tm = fmaxf(tm, p[i]);
        tm = fmaxf(tm, __shfl_xor(tm, 16));
        tm = fmaxf(tm, __shfl_xor(tm, 32));
        float mn = fmaxf(m_r, tm);
        float fscale = exp2f(m_r - mn);
        m_r = mn;
        float rs = 0.f;
        #pragma unroll
        for (int i = 0; i < 16; ++i) { p[i] = exp2f(p[i] - mn); rs += p[i]; }
        rs += __shfl_xor(rs, 16);
        rs += __shfl_xor(rs, 32);
        l_r = l_r * fscale + rs;
        #pragma unroll
        for (int ht = 0; ht < 8; ++ht) oacc[ht] *= fscale;

        #pragma unroll
        for (int st = 0; st < 4; ++st) {
            uint2 w;
            w.x = pk2(p[st * 4 + 0], p[st * 4 + 1]);
            w.y = pk2(p[st * 4 + 2], p[st * 4 + 3]);
            *(uint2*)&p_sh[l15 * 36 + st * 8 + g * 2] = w;
        }
        bf16x8 pa0 = *(const bf16x8*)&p_sh[l15 * 36 + g * 4];
        bf16x8 pa1 = *(const bf16x8*)&p_sh[l15 * 36 + 16 + g * 4];

        #pragma unroll
        for (int ht = 0; ht < 8; ++ht) {
            bf16x8 v0 = *(const bf16x8*)((const char*)sVc +
                            (ht * 16 + l15) * 128 + ((g * 16) ^ kswz));
            bf16x8 v1 = *(const bf16x8*)((const char*)sVc +
                            (ht * 16 + l15) * 128 + ((64 + g * 16) ^ kswz));
            oacc[ht] = __builtin_amdgcn_mfma_f32_16x16x32_bf16(v0, pa0, oacc[ht], 0, 0, 0);
            oacc[ht] = __builtin_amdgcn_mfma_f32_16x16x32_bf16(v1, pa1, oacc[ht], 0, 0, 0);
        }
        __syncthreads();
    }

    float inv_l = 1.0f / l_r;
    #pragma unroll
    for (int ht = 0; ht < 8; ++ht) {
        uint2 o;
        o.x = pk2(oacc[ht][0] * inv_l, oacc[ht][1] * inv_l);
        o.y = pk2(oacc[ht][2] * inv_l, oacc[ht][3] * inv_l);
        *(uint2*)&Ob[(size_t)(b * S_LEN + q0 + l15) * 512 + h * 128 + ht * 16 + g * 4] = o;
    }
}

extern "C" void kernel_launch(void* const* d_in, const int* in_sizes, int n_in,
                              void* d_out, int out_size, void* d_ws, size_t ws_size,
                              hipStream_t stream) {
    const float* x         = (const float*)d_in[0];
    const int*   positions = (const int*)d_in[1];
    const float* wq        = (const float*)d_in[2];
    const float* wk        = (const float*)d_in[3];
    const float* wv        = (const float*)d_in[4];
    const float* wo        = (const float*)d_in[5];
    float* out = (float*)d_out;

    // d_out (134.2MB): [0,67.1) = Xb bf16, [67.1,79.7) = P1 bf16 (dead before GEMM2 writes)
    u16* Xb = (u16*)d_out;
    u16* P1 = (u16*)((char*)d_out + 67108864);

    char* ws = (char*)d_ws;
    size_t off = 0;
    auto alloc = [&](size_t bytes) { void* p = ws + off; off = (off + bytes + 255) & ~(size_t)255; return p; };
    u16*   Wqkv = (u16*)alloc(768ull * 4096 * 2);
    u16*   WoT  = (u16*)alloc(4096ull * 512 * 2);
    u16*   P0   = (u16*)alloc(8192ull * 768 * 2);
    u16*   Qb   = (u16*)alloc(8192ull * 512 * 2);
    u16*   Kb   = (u16*)alloc(8192ull * 128 * 2);
    u16*   Vt   = (u16*)alloc(4ull * 128 * 2048 * 2);
    u16*   Ob   = (u16*)alloc(8192ull * 512 * 2);

    conv_x_kernel<<<(8192 * 4096) / (4 * 256), 256, 0, stream>>>(x, Xb);
    pack_wqkv_kernel<<<dim3(24, 128), 256, 0, stream>>>(wq, wk, wv, Wqkv);
    pack_wo_kernel<<<dim3(128, 16), 256, 0, stream>>>(wo, WoT);

    // GEMM1 (bf16 Xb): split-K=2, z=0 -> P0, z=1 -> P1 (both bf16)
    gemm_pipe_bf<<<dim3(6, 64, 2), 256, 0, stream>>>(Xb, Wqkv, P0, P1, 768, 4096, 2048);

    rope_rms_kernel<<<(8192 * 5) / 4, 256, 0, stream>>>(P0, P1, positions, Qb, Kb);
    vtrans_kernel<<<128, 256, 0, stream>>>(P0, P1, Vt);

    attn_kernel<<<512, 256, 0, stream>>>(Qb, Kb, Vt, Ob);

    // GEMM2 (bf16 Ob) -> f32 out
    gemm_pipe<<<dim3(32, 64), 256, 0, stream>>>(Ob, WoT, out, 4096, 512);
}

// Round 16
// 238.538 us; speedup vs baseline: 1.3143x; 1.0193x over previous
//
#include <hip/hip_runtime.h>

typedef unsigned short u16;
typedef unsigned int u32;
typedef __bf16 bf16x8 __attribute__((ext_vector_type(8)));
typedef float f32x4 __attribute__((ext_vector_type(4)));

#define S_LEN 2048

__device__ __forceinline__ u16 f2b(float f) {
    union { float f; unsigned u; } a; a.f = f;
    unsigned u = a.u;
    unsigned r = u + 0x7fffu + ((u >> 16) & 1u);
    return (u16)(r >> 16);
}

__device__ __forceinline__ float b2f(u32 h) {
    union { u32 u; float f; } c; c.u = h << 16; return c.f;
}

__device__ __forceinline__ u32 pk2(float a, float b) {
    return (u32)f2b(a) | ((u32)f2b(b) << 16);
}

__device__ __forceinline__ void gload16(const void* g, void* l) {
    __builtin_amdgcn_global_load_lds(
        (const __attribute__((address_space(1))) unsigned int*)g,
        (__attribute__((address_space(3))) unsigned int*)l,
        16, 0, 0);
}

// ---------- x f32 -> bf16 ----------
__global__ __launch_bounds__(256) void conv_x_kernel(const float* __restrict__ x,
                                                     u16* __restrict__ xb) {
    long i = ((long)blockIdx.x * 256 + threadIdx.x) * 4;
    float4 v = *(const float4*)(x + i);
    ushort4 o;
    o.x = f2b(v.x); o.y = f2b(v.y); o.z = f2b(v.z); o.w = f2b(v.w);
    *(ushort4*)(xb + i) = o;
}

// ---------- transpose-pack wq|wk|wv -> W[768][4096] bf16 (LDS 32x32 tiles) ----------
__global__ __launch_bounds__(256) void pack_wqkv_kernel(const float* __restrict__ wq,
                                                        const float* __restrict__ wk,
                                                        const float* __restrict__ wv,
                                                        u16* __restrict__ W) {
    __shared__ float t[32][33];
    const int n0 = blockIdx.x * 32, k0 = blockIdx.y * 32;
    const int tid = threadIdx.x;
    const int cc = tid & 31, rr = tid >> 5;
    #pragma unroll
    for (int i = 0; i < 4; ++i) {
        int k = k0 + rr + i * 8, n = n0 + cc;
        float v;
        if (n < 512)      v = wq[(size_t)k * 512 + n];
        else if (n < 640) v = wk[(size_t)k * 128 + (n - 512)];
        else              v = wv[(size_t)k * 128 + (n - 640)];
        t[rr + i * 8][cc] = v;
    }
    __syncthreads();
    #pragma unroll
    for (int i = 0; i < 4; ++i) {
        int nn = rr + i * 8, kk = cc;
        W[(size_t)(n0 + nn) * 4096 + k0 + kk] = f2b(t[kk][nn]);
    }
}

// ---------- transpose-pack wo[512][4096] -> WoT[4096][512] bf16 ----------
__global__ __launch_bounds__(256) void pack_wo_kernel(const float* __restrict__ wo,
                                                      u16* __restrict__ W) {
    __shared__ float t[32][33];
    const int n0 = blockIdx.x * 32, k0 = blockIdx.y * 32;
    const int tid = threadIdx.x;
    const int cc = tid & 31, rr = tid >> 5;
    #pragma unroll
    for (int i = 0; i < 4; ++i)
        t[rr + i * 8][cc] = wo[(size_t)(k0 + rr + i * 8) * 4096 + n0 + cc];
    __syncthreads();
    #pragma unroll
    for (int i = 0; i < 4; ++i)
        W[(size_t)(n0 + rr + i * 8) * 512 + k0 + cc] = f2b(t[cc][rr + i * 8]);
}

// ---------- GEMM1: C(bf16) = A(MxK,bf16) * B^T(NxK,bf16), 128^2, ring-3 (r10/r15) ----------
__global__ __launch_bounds__(256) void gemm_pipe_bf(const u16* __restrict__ A,
                                                    const u16* __restrict__ B,
                                                    u16* __restrict__ C0,
                                                    u16* __restrict__ C1,
                                                    int N, int K, int kBase) {
    __shared__ __align__(16) u16 sA[3][128 * 32];
    __shared__ __align__(16) u16 sB[3][128 * 32];
    const int tid = threadIdx.x;
    const int lane = tid & 63, wid = tid >> 6;
    const int wr = wid >> 1, wc = wid & 1;
    const int l15 = lane & 15, g = lane >> 4;
    const int srow = lane >> 2;
    const int swzc = ((lane & 3) * 8) ^ (((lane >> 3) & 3) << 3);
    const int rswz = ((l15 >> 1) & 3) << 3;

    const u32 lid = blockIdx.x + gridDim.x * (blockIdx.y + gridDim.y * blockIdx.z);
    const u32 xcd = lid & 7, slot = lid >> 3;
    const u32 per = gridDim.x * gridDim.z;
    const u32 bml = slot / per;
    const u32 rmd = slot - bml * per;
    const int bn = rmd % gridDim.x;
    const int z  = rmd / gridDim.x;
    const int bm = xcd * (gridDim.y >> 3) + bml;

    u16* C = z ? C1 : C0;
    const int k0 = z * kBase;
    const int nt = kBase / 32;

    const int ch0 = wid * 2, ch1 = wid * 2 + 1;
    const int r0 = ch0 * 16 + srow, r1 = ch1 * 16 + srow;

    auto stage = [&](int buf, int kt) {
        gload16(&A[(size_t)(bm * 128 + r0) * K + kt + swzc], &sA[buf][ch0 * 512]);
        gload16(&A[(size_t)(bm * 128 + r1) * K + kt + swzc], &sA[buf][ch1 * 512]);
        gload16(&B[(size_t)(bn * 128 + r0) * K + kt + swzc], &sB[buf][ch0 * 512]);
        gload16(&B[(size_t)(bn * 128 + r1) * K + kt + swzc], &sB[buf][ch1 * 512]);
    };

    f32x4 acc[4][4] = {};

    stage(0, k0);
    stage(1, k0 + 32);

    for (int t = 0; t < nt; ++t) {
        if (t + 1 < nt) asm volatile("s_waitcnt vmcnt(4)" ::: "memory");
        else            asm volatile("s_waitcnt vmcnt(0)" ::: "memory");
        __builtin_amdgcn_s_barrier();
        __builtin_amdgcn_sched_barrier(0);
        if (t + 2 < nt) stage((t + 2) % 3, k0 + (t + 2) * 32);
        const int cur = t % 3;
        bf16x8 af[4], bfr[4];
        #pragma unroll
        for (int m = 0; m < 4; ++m)
            af[m] = *(const bf16x8*)&sA[cur][(wr * 64 + m * 16 + l15) * 32 + (g * 8 ^ rswz)];
        #pragma unroll
        for (int n = 0; n < 4; ++n)
            bfr[n] = *(const bf16x8*)&sB[cur][(wc * 64 + n * 16 + l15) * 32 + (g * 8 ^ rswz)];
        #pragma unroll
        for (int m = 0; m < 4; ++m)
            #pragma unroll
            for (int n = 0; n < 4; ++n)
                acc[m][n] = __builtin_amdgcn_mfma_f32_16x16x32_bf16(af[m], bfr[n], acc[m][n], 0, 0, 0);
    }

    #pragma unroll
    for (int m = 0; m < 4; ++m) {
        int row = bm * 128 + wr * 64 + m * 16 + g * 4;
        #pragma unroll
        for (int n = 0; n < 4; ++n) {
            int col = bn * 128 + wc * 64 + n * 16 + l15;
            #pragma unroll
            for (int rr = 0; rr < 4; ++rr)
                C[(size_t)(row + rr) * N + col] = f2b(acc[m][n][rr]);
        }
    }
}

// ---------- GEMM2: C(f32) = A(MxK,bf16) * B^T(NxK,bf16), 256^2 tile, ring-3 ----------
// Mechanical rescale of the r10 ring: 8 waves (2Mx4N, wave tile 128x64), BK=32,
// 16 stage-chunks of 16 rows, same vmcnt(4) / barrier / stage(t+2) schedule,
// same XOR swizzle (row stride 64B), same XCD remap. LDS 96KB -> 1 block/CU.
__global__ __launch_bounds__(512) void gemm_pipe256(const u16* __restrict__ A,
                                                    const u16* __restrict__ B,
                                                    float* __restrict__ C,
                                                    int N, int K) {
    __shared__ __align__(16) u16 sA[3][256 * 32];
    __shared__ __align__(16) u16 sB[3][256 * 32];
    const int tid = threadIdx.x;
    const int lane = tid & 63, wid = tid >> 6;     // 8 waves
    const int wr = wid >> 2, wc = wid & 3;         // 2 x 4 wave grid
    const int l15 = lane & 15, g = lane >> 4;
    const int srow = lane >> 2;
    const int swzc = ((lane & 3) * 8) ^ (((lane >> 3) & 3) << 3);
    const int rswz = ((l15 >> 1) & 3) << 3;

    const u32 lid = blockIdx.x + gridDim.x * blockIdx.y;
    const u32 xcd = lid & 7, slot = lid >> 3;
    const u32 per = gridDim.x;
    const u32 bml = slot / per;
    const int bn = slot - bml * per;
    const int bm = xcd * (gridDim.y >> 3) + bml;

    const int nt = K / 32;
    const int ch0 = wid * 2, ch1 = wid * 2 + 1;    // chunks 0..15 of 16 rows
    const int r0 = ch0 * 16 + srow, r1 = ch1 * 16 + srow;

    auto stage = [&](int buf, int kt) {
        gload16(&A[(size_t)(bm * 256 + r0) * K + kt + swzc], &sA[buf][ch0 * 512]);
        gload16(&A[(size_t)(bm * 256 + r1) * K + kt + swzc], &sA[buf][ch1 * 512]);
        gload16(&B[(size_t)(bn * 256 + r0) * K + kt + swzc], &sB[buf][ch0 * 512]);
        gload16(&B[(size_t)(bn * 256 + r1) * K + kt + swzc], &sB[buf][ch1 * 512]);
    };

    f32x4 acc[8][4] = {};

    stage(0, 0);
    stage(1, 32);

    for (int t = 0; t < nt; ++t) {
        if (t + 1 < nt) asm volatile("s_waitcnt vmcnt(4)" ::: "memory");
        else            asm volatile("s_waitcnt vmcnt(0)" ::: "memory");
        __builtin_amdgcn_s_barrier();
        __builtin_amdgcn_sched_barrier(0);
        if (t + 2 < nt) stage((t + 2) % 3, (t + 2) * 32);
        const int cur = t % 3;
        bf16x8 af[8], bfr[4];
        #pragma unroll
        for (int m = 0; m < 8; ++m)
            af[m] = *(const bf16x8*)&sA[cur][(wr * 128 + m * 16 + l15) * 32 + (g * 8 ^ rswz)];
        #pragma unroll
        for (int n = 0; n < 4; ++n)
            bfr[n] = *(const bf16x8*)&sB[cur][(wc * 64 + n * 16 + l15) * 32 + (g * 8 ^ rswz)];
        #pragma unroll
        for (int m = 0; m < 8; ++m)
            #pragma unroll
            for (int n = 0; n < 4; ++n)
                acc[m][n] = __builtin_amdgcn_mfma_f32_16x16x32_bf16(af[m], bfr[n], acc[m][n], 0, 0, 0);
    }

    #pragma unroll
    for (int m = 0; m < 8; ++m) {
        int row = bm * 256 + wr * 128 + m * 16 + g * 4;
        #pragma unroll
        for (int n = 0; n < 4; ++n) {
            int col = bn * 256 + wc * 64 + n * 16 + l15;
            #pragma unroll
            for (int rr = 0; rr < 4; ++rr)
                C[(size_t)(row + rr) * N + col] = acc[m][n][rr];
        }
    }
}

// ---------- RoPE + RMSNorm + scales: (P0+P1)(bf16) -> Qb/Kb (bf16) ----------
__global__ __launch_bounds__(256) void rope_rms_kernel(const u16* __restrict__ P0,
                                                       const u16* __restrict__ P1,
                                                       const int* __restrict__ positions,
                                                       u16* __restrict__ Qb,
                                                       u16* __restrict__ Kb) {
    const int w = blockIdx.x * 4 + (threadIdx.x >> 6);
    const int lane = threadIdx.x & 63;
    const int row = w / 5, head = w - row * 5;
    const int s = row & (S_LEN - 1);

    float pos = (float)positions[s];
    float ex = (float)(2 * lane) * (1.0f / 128.0f);
    float inv_freq = __expf(-ex * 13.122363377404328f);   // ln(500000)
    float ang = pos * inv_freq;
    float c, sn;
    __sincosf(ang, &sn, &c);

    size_t off = (size_t)row * 768 + head * 128 + 2 * lane;
    u32 pa = *(const u32*)&P0[off];
    u32 pb = *(const u32*)&P1[off];
    float x0 = b2f(pa & 0xffffu) + b2f(pb & 0xffffu);
    float x1 = b2f(pa >> 16)     + b2f(pb >> 16);
    float o0 = x0 * c - x1 * sn;
    float o1 = x0 * sn + x1 * c;

    float ss = o0 * o0 + o1 * o1;
    #pragma unroll
    for (int m = 1; m < 64; m <<= 1) ss += __shfl_xor(ss, m, 64);
    float rms = rsqrtf(ss * (1.0f / 128.0f) + 1e-6f);

    if (head < 4) {
        float ascale = logf(floorf((pos + 1.0f) * (1.0f / 8192.0f)) + 1.0f) * 0.1f + 1.0f;
        // fold 1/sqrt(128) * (1/ln2) so attention uses exp2
        float mult = rms * ascale * 0.12751743f;
        *(u32*)&Qb[(size_t)row * 512 + head * 128 + 2 * lane] = pk2(o0 * mult, o1 * mult);
    } else {
        *(u32*)&Kb[(size_t)row * 128 + 2 * lane] = pk2(o0 * rms, o1 * rms);
    }
}

// ---------- V slice of (P0+P1)(bf16) -> Vt[b][d][s] bf16 (LDS tile transpose) ----------
__global__ __launch_bounds__(256) void vtrans_kernel(const u16* __restrict__ P0,
                                                     const u16* __restrict__ P1,
                                                     u16* __restrict__ Vt) {
    __shared__ u16 tile[128][72];
    const int bi = blockIdx.x >> 5, st = blockIdx.x & 31;
    const int s0 = st * 64;
    const int tid = threadIdx.x;
    #pragma unroll
    for (int i = 0; i < 8; ++i) {
        int idx = i * 256 + tid;
        int r = idx >> 5, c4 = idx & 31;
        size_t off = (size_t)(bi * S_LEN + s0 + r) * 768 + 640 + c4 * 4;
        uint2 a = *(const uint2*)&P0[off];
        uint2 b = *(const uint2*)&P1[off];
        tile[c4 * 4 + 0][r] = f2b(b2f(a.x & 0xffffu) + b2f(b.x & 0xffffu));
        tile[c4 * 4 + 1][r] = f2b(b2f(a.x >> 16)     + b2f(b.x >> 16));
        tile[c4 * 4 + 2][r] = f2b(b2f(a.y & 0xffffu) + b2f(b.y & 0xffffu));
        tile[c4 * 4 + 3][r] = f2b(b2f(a.y >> 16)     + b2f(b.y >> 16));
    }
    __syncthreads();
    #pragma unroll
    for (int i = 0; i < 4; ++i) {
        int idx = i * 256 + tid;
        int d = idx >> 3, sl = idx & 7;
        bf16x8 v = *(const bf16x8*)&tile[d][sl * 8];
        *(bf16x8*)&Vt[((size_t)bi * 128 + d) * S_LEN + s0 + sl * 8] = v;
    }
}

// ---------- flash attention (causal, GQA 4:1) ----------
// block = (b, q-tile of 16); 4 waves = 4 heads SHARING LDS-staged K/V (dbuf, swizzled).
__global__ __launch_bounds__(256) void attn_kernel(const u16* __restrict__ Qb,
                                                   const u16* __restrict__ Kb,
                                                   const u16* __restrict__ Vt,
                                                   u16* __restrict__ Ob) {
    __shared__ __align__(16) u16 sK[2][64 * 128];
    __shared__ __align__(16) u16 sV[2][128 * 64];
    __shared__ __align__(16) u32 p_all[4][16 * 36];
    const int tid = threadIdx.x;
    const int lane = tid & 63, wid = tid >> 6;    // wid = head
    const int l15 = lane & 15, g = lane >> 4;
    const int bid = blockIdx.x;
    const int qt = 127 - (bid >> 2);              // longest q-tiles first
    const int b = bid & 3;
    const int h = wid;
    const int q0 = qt * 16;
    const int kswz = (l15 & 7) << 4;              // read-side XOR (bytes)

    u32* p_sh = p_all[wid];

    bf16x8 qf[4];
    {
        const u16* qrow = Qb + (size_t)(b * S_LEN + q0 + l15) * 512 + h * 128 + g * 8;
        #pragma unroll
        for (int c = 0; c < 4; ++c) qf[c] = *(const bf16x8*)(qrow + c * 32);
    }
    const u16* Kbase = Kb + (size_t)b * S_LEN * 128;
    const u16* Vbase = Vt + (size_t)b * 128 * S_LEN;

    const int klr = lane >> 4, klo = (lane & 15) * 16;
    const int vlr = lane >> 3, vlo = (lane & 7) * 16;

    auto stage = [&](int buf, int kv0) {
        #pragma unroll
        for (int j = 0; j < 4; ++j) {
            int r0 = wid * 16 + j * 4;
            int row = r0 + klr;
            gload16((const char*)Kbase + (size_t)(kv0 + row) * 256 + (klo ^ ((row & 7) << 4)),
                    &sK[buf][r0 * 128]);
        }
        #pragma unroll
        for (int j = 0; j < 4; ++j) {
            int r0 = wid * 32 + j * 8;
            int row = r0 + vlr;
            gload16((const char*)Vbase + (size_t)row * (S_LEN * 2) + (size_t)kv0 * 2 + (vlo ^ ((row & 7) << 4)),
                    &sV[buf][r0 * 64]);
        }
    };

    f32x4 oacc[8] = {};
    float m_r = -1e30f, l_r = 0.f;

    const int nt = (q0 >> 6) + 1;
    stage(0, 0);
    __syncthreads();

    for (int t = 0; t < nt; ++t) {
        const u16* sKc = sK[t & 1];
        const u16* sVc = sV[t & 1];
        if (t + 1 < nt) stage((t + 1) & 1, (t + 1) * 64);
        const int kv0 = t * 64;
        const bool masked = (t == nt - 1);

        f32x4 sf[4] = {};
        #pragma unroll
        for (int st = 0; st < 4; ++st) {
            #pragma unroll
            for (int c = 0; c < 4; ++c) {
                bf16x8 kf = *(const bf16x8*)((const char*)sKc +
                                (st * 16 + l15) * 256 + ((c * 64 + g * 16) ^ kswz));
                sf[st] = __builtin_amdgcn_mfma_f32_16x16x32_bf16(kf, qf[c], sf[st], 0, 0, 0);
            }
        }
        float p[16];
        #pragma unroll
        for (int st = 0; st < 4; ++st)
            #pragma unroll
            for (int r = 0; r < 4; ++r) p[st * 4 + r] = sf[st][r];
        if (masked) {
            #pragma unroll
            for (int st = 0; st < 4; ++st)
                #pragma unroll
                for (int r = 0; r < 4; ++r) {
                    int kp = kv0 + st * 16 + g * 4 + r;
                    if (kp > q0 + l15) p[st * 4 + r] = -1e30f;
                }
        }
        float tm = p[0];
        #pragma unroll
        for (int i = 1; i < 16; ++i) tm = fmaxf(tm, p[i]);
        tm = fmaxf(tm, __shfl_xor(tm, 16));
        tm = fmaxf(tm, __shfl_xor(tm, 32));
        float mn = fmaxf(m_r, tm);
        float fscale = exp2f(m_r - mn);
        m_r = mn;
        float rs = 0.f;
        #pragma unroll
        for (int i = 0; i < 16; ++i) { p[i] = exp2f(p[i] - mn); rs += p[i]; }
        rs += __shfl_xor(rs, 16);
        rs += __shfl_xor(rs, 32);
        l_r = l_r * fscale + rs;
        #pragma unroll
        for (int ht = 0; ht < 8; ++ht) oacc[ht] *= fscale;

        #pragma unroll
        for (int st = 0; st < 4; ++st) {
            uint2 w;
            w.x = pk2(p[st * 4 + 0], p[st * 4 + 1]);
            w.y = pk2(p[st * 4 + 2], p[st * 4 + 3]);
            *(uint2*)&p_sh[l15 * 36 + st * 8 + g * 2] = w;
        }
        bf16x8 pa0 = *(const bf16x8*)&p_sh[l15 * 36 + g * 4];
        bf16x8 pa1 = *(const bf16x8*)&p_sh[l15 * 36 + 16 + g * 4];

        #pragma unroll
        for (int ht = 0; ht < 8; ++ht) {
            bf16x8 v0 = *(const bf16x8*)((const char*)sVc +
                            (ht * 16 + l15) * 128 + ((g * 16) ^ kswz));
            bf16x8 v1 = *(const bf16x8*)((const char*)sVc +
                            (ht * 16 + l15) * 128 + ((64 + g * 16) ^ kswz));
            oacc[ht] = __builtin_amdgcn_mfma_f32_16x16x32_bf16(v0, pa0, oacc[ht], 0, 0, 0);
            oacc[ht] = __builtin_amdgcn_mfma_f32_16x16x32_bf16(v1, pa1, oacc[ht], 0, 0, 0);
        }
        __syncthreads();
    }

    float inv_l = 1.0f / l_r;
    #pragma unroll
    for (int ht = 0; ht < 8; ++ht) {
        uint2 o;
        o.x = pk2(oacc[ht][0] * inv_l, oacc[ht][1] * inv_l);
        o.y = pk2(oacc[ht][2] * inv_l, oacc[ht][3] * inv_l);
        *(uint2*)&Ob[(size_t)(b * S_LEN + q0 + l15) * 512 + h * 128 + ht * 16 + g * 4] = o;
    }
}

extern "C" void kernel_launch(void* const* d_in, const int* in_sizes, int n_in,
                              void* d_out, int out_size, void* d_ws, size_t ws_size,
                              hipStream_t stream) {
    const float* x         = (const float*)d_in[0];
    const int*   positions = (const int*)d_in[1];
    const float* wq        = (const float*)d_in[2];
    const float* wk        = (const float*)d_in[3];
    const float* wv        = (const float*)d_in[4];
    const float* wo        = (const float*)d_in[5];
    float* out = (float*)d_out;

    // d_out (134.2MB): [0,67.1) = Xb bf16, [67.1,79.7) = P1 bf16 (dead before GEMM2 writes)
    u16* Xb = (u16*)d_out;
    u16* P1 = (u16*)((char*)d_out + 67108864);

    char* ws = (char*)d_ws;
    size_t off = 0;
    auto alloc = [&](size_t bytes) { void* p = ws + off; off = (off + bytes + 255) & ~(size_t)255; return p; };
    u16*   Wqkv = (u16*)alloc(768ull * 4096 * 2);
    u16*   WoT  = (u16*)alloc(4096ull * 512 * 2);
    u16*   P0   = (u16*)alloc(8192ull * 768 * 2);
    u16*   Qb   = (u16*)alloc(8192ull * 512 * 2);
    u16*   Kb   = (u16*)alloc(8192ull * 128 * 2);
    u16*   Vt   = (u16*)alloc(4ull * 128 * 2048 * 2);
    u16*   Ob   = (u16*)alloc(8192ull * 512 * 2);

    conv_x_kernel<<<(8192 * 4096) / (4 * 256), 256, 0, stream>>>(x, Xb);
    pack_wqkv_kernel<<<dim3(24, 128), 256, 0, stream>>>(wq, wk, wv, Wqkv);
    pack_wo_kernel<<<dim3(128, 16), 256, 0, stream>>>(wo, WoT);

    // GEMM1 (bf16 Xb): 128^2 tile, split-K=2, z=0 -> P0, z=1 -> P1 (both bf16)
    gemm_pipe_bf<<<dim3(6, 64, 2), 256, 0, stream>>>(Xb, Wqkv, P0, P1, 768, 4096, 2048);

    rope_rms_kernel<<<(8192 * 5) / 4, 256, 0, stream>>>(P0, P1, positions, Qb, Kb);
    vtrans_kernel<<<128, 256, 0, stream>>>(P0, P1, Vt);

    attn_kernel<<<512, 256, 0, stream>>>(Qb, Kb, Vt, Ob);

    // GEMM2 (bf16 Ob) -> f32 out: 256^2 tile, 8 waves
    gemm_pipe256<<<dim3(4096 / 256, 8192 / 256), 512, 0, stream>>>(Ob, WoT, out, 4096, 512);
}

// Round 17
// 237.861 us; speedup vs baseline: 1.3181x; 1.0028x over previous
//
#include <hip/hip_runtime.h>

typedef unsigned short u16;
typedef unsigned int u32;
typedef __bf16 bf16x8 __attribute__((ext_vector_type(8)));
typedef float f32x4 __attribute__((ext_vector_type(4)));

#define S_LEN 2048

__device__ __forceinline__ u16 f2b(float f) {
    union { float f; unsigned u; } a; a.f = f;
    unsigned u = a.u;
    unsigned r = u + 0x7fffu + ((u >> 16) & 1u);
    return (u16)(r >> 16);
}

__device__ __forceinline__ float b2f(u32 h) {
    union { u32 u; float f; } c; c.u = h << 16; return c.f;
}

__device__ __forceinline__ u32 pk2(float a, float b) {
    return (u32)f2b(a) | ((u32)f2b(b) << 16);
}

__device__ __forceinline__ void gload16(const void* g, void* l) {
    __builtin_amdgcn_global_load_lds(
        (const __attribute__((address_space(1))) unsigned int*)g,
        (__attribute__((address_space(3))) unsigned int*)l,
        16, 0, 0);
}

// ---------- x f32 -> bf16 ----------
__global__ __launch_bounds__(256) void conv_x_kernel(const float* __restrict__ x,
                                                     u16* __restrict__ xb) {
    long i = ((long)blockIdx.x * 256 + threadIdx.x) * 4;
    float4 v = *(const float4*)(x + i);
    ushort4 o;
    o.x = f2b(v.x); o.y = f2b(v.y); o.z = f2b(v.z); o.w = f2b(v.w);
    *(ushort4*)(xb + i) = o;
}

// ---------- transpose-pack wq|wk|wv -> W[768][4096] bf16 (LDS 32x32 tiles) ----------
__global__ __launch_bounds__(256) void pack_wqkv_kernel(const float* __restrict__ wq,
                                                        const float* __restrict__ wk,
                                                        const float* __restrict__ wv,
                                                        u16* __restrict__ W) {
    __shared__ float t[32][33];
    const int n0 = blockIdx.x * 32, k0 = blockIdx.y * 32;
    const int tid = threadIdx.x;
    const int cc = tid & 31, rr = tid >> 5;
    #pragma unroll
    for (int i = 0; i < 4; ++i) {
        int k = k0 + rr + i * 8, n = n0 + cc;
        float v;
        if (n < 512)      v = wq[(size_t)k * 512 + n];
        else if (n < 640) v = wk[(size_t)k * 128 + (n - 512)];
        else              v = wv[(size_t)k * 128 + (n - 640)];
        t[rr + i * 8][cc] = v;
    }
    __syncthreads();
    #pragma unroll
    for (int i = 0; i < 4; ++i) {
        int nn = rr + i * 8, kk = cc;
        W[(size_t)(n0 + nn) * 4096 + k0 + kk] = f2b(t[kk][nn]);
    }
}

// ---------- transpose-pack wo[512][4096] -> WoT[4096][512] bf16 ----------
__global__ __launch_bounds__(256) void pack_wo_kernel(const float* __restrict__ wo,
                                                      u16* __restrict__ W) {
    __shared__ float t[32][33];
    const int n0 = blockIdx.x * 32, k0 = blockIdx.y * 32;
    const int tid = threadIdx.x;
    const int cc = tid & 31, rr = tid >> 5;
    #pragma unroll
    for (int i = 0; i < 4; ++i)
        t[rr + i * 8][cc] = wo[(size_t)(k0 + rr + i * 8) * 4096 + n0 + cc];
    __syncthreads();
    #pragma unroll
    for (int i = 0; i < 4; ++i)
        W[(size_t)(n0 + rr + i * 8) * 512 + k0 + cc] = f2b(t[cc][rr + i * 8]);
}

// ---------- GEMM1: C(bf16) = A(MxK,bf16) * B^T(NxK,bf16), 128^2, ring-3 (r10/r15) ----------
__global__ __launch_bounds__(256) void gemm_pipe_bf(const u16* __restrict__ A,
                                                    const u16* __restrict__ B,
                                                    u16* __restrict__ C0,
                                                    u16* __restrict__ C1,
                                                    int N, int K, int kBase) {
    __shared__ __align__(16) u16 sA[3][128 * 32];
    __shared__ __align__(16) u16 sB[3][128 * 32];
    const int tid = threadIdx.x;
    const int lane = tid & 63, wid = tid >> 6;
    const int wr = wid >> 1, wc = wid & 1;
    const int l15 = lane & 15, g = lane >> 4;
    const int srow = lane >> 2;
    const int swzc = ((lane & 3) * 8) ^ (((lane >> 3) & 3) << 3);
    const int rswz = ((l15 >> 1) & 3) << 3;

    const u32 lid = blockIdx.x + gridDim.x * (blockIdx.y + gridDim.y * blockIdx.z);
    const u32 xcd = lid & 7, slot = lid >> 3;
    const u32 per = gridDim.x * gridDim.z;
    const u32 bml = slot / per;
    const u32 rmd = slot - bml * per;
    const int bn = rmd % gridDim.x;
    const int z  = rmd / gridDim.x;
    const int bm = xcd * (gridDim.y >> 3) + bml;

    u16* C = z ? C1 : C0;
    const int k0 = z * kBase;
    const int nt = kBase / 32;

    const int ch0 = wid * 2, ch1 = wid * 2 + 1;
    const int r0 = ch0 * 16 + srow, r1 = ch1 * 16 + srow;

    auto stage = [&](int buf, int kt) {
        gload16(&A[(size_t)(bm * 128 + r0) * K + kt + swzc], &sA[buf][ch0 * 512]);
        gload16(&A[(size_t)(bm * 128 + r1) * K + kt + swzc], &sA[buf][ch1 * 512]);
        gload16(&B[(size_t)(bn * 128 + r0) * K + kt + swzc], &sB[buf][ch0 * 512]);
        gload16(&B[(size_t)(bn * 128 + r1) * K + kt + swzc], &sB[buf][ch1 * 512]);
    };

    f32x4 acc[4][4] = {};

    stage(0, k0);
    stage(1, k0 + 32);

    for (int t = 0; t < nt; ++t) {
        if (t + 1 < nt) asm volatile("s_waitcnt vmcnt(4)" ::: "memory");
        else            asm volatile("s_waitcnt vmcnt(0)" ::: "memory");
        __builtin_amdgcn_s_barrier();
        __builtin_amdgcn_sched_barrier(0);
        if (t + 2 < nt) stage((t + 2) % 3, k0 + (t + 2) * 32);
        const int cur = t % 3;
        bf16x8 af[4], bfr[4];
        #pragma unroll
        for (int m = 0; m < 4; ++m)
            af[m] = *(const bf16x8*)&sA[cur][(wr * 64 + m * 16 + l15) * 32 + (g * 8 ^ rswz)];
        #pragma unroll
        for (int n = 0; n < 4; ++n)
            bfr[n] = *(const bf16x8*)&sB[cur][(wc * 64 + n * 16 + l15) * 32 + (g * 8 ^ rswz)];
        #pragma unroll
        for (int m = 0; m < 4; ++m)
            #pragma unroll
            for (int n = 0; n < 4; ++n)
                acc[m][n] = __builtin_amdgcn_mfma_f32_16x16x32_bf16(af[m], bfr[n], acc[m][n], 0, 0, 0);
    }

    #pragma unroll
    for (int m = 0; m < 4; ++m) {
        int row = bm * 128 + wr * 64 + m * 16 + g * 4;
        #pragma unroll
        for (int n = 0; n < 4; ++n) {
            int col = bn * 128 + wc * 64 + n * 16 + l15;
            #pragma unroll
            for (int rr = 0; rr < 4; ++rr)
                C[(size_t)(row + rr) * N + col] = f2b(acc[m][n][rr]);
        }
    }
}

// ---------- GEMM2: C(f32) = A(MxK,bf16) * B^T(NxK,bf16), 256^2 tile, ring-3 (r16) ----------
__global__ __launch_bounds__(512) void gemm_pipe256(const u16* __restrict__ A,
                                                    const u16* __restrict__ B,
                                                    float* __restrict__ C,
                                                    int N, int K) {
    __shared__ __align__(16) u16 sA[3][256 * 32];
    __shared__ __align__(16) u16 sB[3][256 * 32];
    const int tid = threadIdx.x;
    const int lane = tid & 63, wid = tid >> 6;     // 8 waves
    const int wr = wid >> 2, wc = wid & 3;         // 2 x 4 wave grid
    const int l15 = lane & 15, g = lane >> 4;
    const int srow = lane >> 2;
    const int swzc = ((lane & 3) * 8) ^ (((lane >> 3) & 3) << 3);
    const int rswz = ((l15 >> 1) & 3) << 3;

    const u32 lid = blockIdx.x + gridDim.x * blockIdx.y;
    const u32 xcd = lid & 7, slot = lid >> 3;
    const u32 per = gridDim.x;
    const u32 bml = slot / per;
    const int bn = slot - bml * per;
    const int bm = xcd * (gridDim.y >> 3) + bml;

    const int nt = K / 32;
    const int ch0 = wid * 2, ch1 = wid * 2 + 1;
    const int r0 = ch0 * 16 + srow, r1 = ch1 * 16 + srow;

    auto stage = [&](int buf, int kt) {
        gload16(&A[(size_t)(bm * 256 + r0) * K + kt + swzc], &sA[buf][ch0 * 512]);
        gload16(&A[(size_t)(bm * 256 + r1) * K + kt + swzc], &sA[buf][ch1 * 512]);
        gload16(&B[(size_t)(bn * 256 + r0) * K + kt + swzc], &sB[buf][ch0 * 512]);
        gload16(&B[(size_t)(bn * 256 + r1) * K + kt + swzc], &sB[buf][ch1 * 512]);
    };

    f32x4 acc[8][4] = {};

    stage(0, 0);
    stage(1, 32);

    for (int t = 0; t < nt; ++t) {
        if (t + 1 < nt) asm volatile("s_waitcnt vmcnt(4)" ::: "memory");
        else            asm volatile("s_waitcnt vmcnt(0)" ::: "memory");
        __builtin_amdgcn_s_barrier();
        __builtin_amdgcn_sched_barrier(0);
        if (t + 2 < nt) stage((t + 2) % 3, (t + 2) * 32);
        const int cur = t % 3;
        bf16x8 af[8], bfr[4];
        #pragma unroll
        for (int m = 0; m < 8; ++m)
            af[m] = *(const bf16x8*)&sA[cur][(wr * 128 + m * 16 + l15) * 32 + (g * 8 ^ rswz)];
        #pragma unroll
        for (int n = 0; n < 4; ++n)
            bfr[n] = *(const bf16x8*)&sB[cur][(wc * 64 + n * 16 + l15) * 32 + (g * 8 ^ rswz)];
        #pragma unroll
        for (int m = 0; m < 8; ++m)
            #pragma unroll
            for (int n = 0; n < 4; ++n)
                acc[m][n] = __builtin_amdgcn_mfma_f32_16x16x32_bf16(af[m], bfr[n], acc[m][n], 0, 0, 0);
    }

    #pragma unroll
    for (int m = 0; m < 8; ++m) {
        int row = bm * 256 + wr * 128 + m * 16 + g * 4;
        #pragma unroll
        for (int n = 0; n < 4; ++n) {
            int col = bn * 256 + wc * 64 + n * 16 + l15;
            #pragma unroll
            for (int rr = 0; rr < 4; ++rr)
                C[(size_t)(row + rr) * N + col] = acc[m][n][rr];
        }
    }
}

// ---------- RoPE + RMSNorm + scales: (P0+P1)(bf16) -> Qb/Kb (bf16) ----------
__global__ __launch_bounds__(256) void rope_rms_kernel(const u16* __restrict__ P0,
                                                       const u16* __restrict__ P1,
                                                       const int* __restrict__ positions,
                                                       u16* __restrict__ Qb,
                                                       u16* __restrict__ Kb) {
    const int w = blockIdx.x * 4 + (threadIdx.x >> 6);
    const int lane = threadIdx.x & 63;
    const int row = w / 5, head = w - row * 5;
    const int s = row & (S_LEN - 1);

    float pos = (float)positions[s];
    float ex = (float)(2 * lane) * (1.0f / 128.0f);
    float inv_freq = __expf(-ex * 13.122363377404328f);   // ln(500000)
    float ang = pos * inv_freq;
    float c, sn;
    __sincosf(ang, &sn, &c);

    size_t off = (size_t)row * 768 + head * 128 + 2 * lane;
    u32 pa = *(const u32*)&P0[off];
    u32 pb = *(const u32*)&P1[off];
    float x0 = b2f(pa & 0xffffu) + b2f(pb & 0xffffu);
    float x1 = b2f(pa >> 16)     + b2f(pb >> 16);
    float o0 = x0 * c - x1 * sn;
    float o1 = x0 * sn + x1 * c;

    float ss = o0 * o0 + o1 * o1;
    #pragma unroll
    for (int m = 1; m < 64; m <<= 1) ss += __shfl_xor(ss, m, 64);
    float rms = rsqrtf(ss * (1.0f / 128.0f) + 1e-6f);

    if (head < 4) {
        float ascale = logf(floorf((pos + 1.0f) * (1.0f / 8192.0f)) + 1.0f) * 0.1f + 1.0f;
        // fold 1/sqrt(128) * (1/ln2) so attention uses exp2
        float mult = rms * ascale * 0.12751743f;
        *(u32*)&Qb[(size_t)row * 512 + head * 128 + 2 * lane] = pk2(o0 * mult, o1 * mult);
    } else {
        *(u32*)&Kb[(size_t)row * 128 + 2 * lane] = pk2(o0 * rms, o1 * rms);
    }
}

// ---------- V slice of (P0+P1)(bf16) -> Vt[b][d][s] bf16 (LDS tile transpose) ----------
__global__ __launch_bounds__(256) void vtrans_kernel(const u16* __restrict__ P0,
                                                     const u16* __restrict__ P1,
                                                     u16* __restrict__ Vt) {
    __shared__ u16 tile[128][72];
    const int bi = blockIdx.x >> 5, st = blockIdx.x & 31;
    const int s0 = st * 64;
    const int tid = threadIdx.x;
    #pragma unroll
    for (int i = 0; i < 8; ++i) {
        int idx = i * 256 + tid;
        int r = idx >> 5, c4 = idx & 31;
        size_t off = (size_t)(bi * S_LEN + s0 + r) * 768 + 640 + c4 * 4;
        uint2 a = *(const uint2*)&P0[off];
        uint2 b = *(const uint2*)&P1[off];
        tile[c4 * 4 + 0][r] = f2b(b2f(a.x & 0xffffu) + b2f(b.x & 0xffffu));
        tile[c4 * 4 + 1][r] = f2b(b2f(a.x >> 16)     + b2f(b.x >> 16));
        tile[c4 * 4 + 2][r] = f2b(b2f(a.y & 0xffffu) + b2f(b.y & 0xffffu));
        tile[c4 * 4 + 3][r] = f2b(b2f(a.y >> 16)     + b2f(b.y >> 16));
    }
    __syncthreads();
    #pragma unroll
    for (int i = 0; i < 4; ++i) {
        int idx = i * 256 + tid;
        int d = idx >> 3, sl = idx & 7;
        bf16x8 v = *(const bf16x8*)&tile[d][sl * 8];
        *(bf16x8*)&Vt[((size_t)bi * 128 + d) * S_LEN + s0 + sl * 8] = v;
    }
}

// ---------- flash attention (causal, GQA 4:1) ----------
// block = (b, q-tile of 16); 4 waves = 4 heads SHARING LDS-staged K/V (dbuf, swizzled).
// r17: T13 defer-max (skip rescale when __all(tm - m_r <= 8)); sum-reduce shuffles
// moved after PV MFMAs (LDS pipe overlaps matrix pipe).
__global__ __launch_bounds__(256) void attn_kernel(const u16* __restrict__ Qb,
                                                   const u16* __restrict__ Kb,
                                                   const u16* __restrict__ Vt,
                                                   u16* __restrict__ Ob) {
    __shared__ __align__(16) u16 sK[2][64 * 128];
    __shared__ __align__(16) u16 sV[2][128 * 64];
    __shared__ __align__(16) u32 p_all[4][16 * 36];
    const int tid = threadIdx.x;
    const int lane = tid & 63, wid = tid >> 6;    // wid = head
    const int l15 = lane & 15, g = lane >> 4;
    const int bid = blockIdx.x;
    const int qt = 127 - (bid >> 2);              // longest q-tiles first
    const int b = bid & 3;
    const int h = wid;
    const int q0 = qt * 16;
    const int kswz = (l15 & 7) << 4;              // read-side XOR (bytes)

    u32* p_sh = p_all[wid];

    bf16x8 qf[4];
    {
        const u16* qrow = Qb + (size_t)(b * S_LEN + q0 + l15) * 512 + h * 128 + g * 8;
        #pragma unroll
        for (int c = 0; c < 4; ++c) qf[c] = *(const bf16x8*)(qrow + c * 32);
    }
    const u16* Kbase = Kb + (size_t)b * S_LEN * 128;
    const u16* Vbase = Vt + (size_t)b * 128 * S_LEN;

    const int klr = lane >> 4, klo = (lane & 15) * 16;
    const int vlr = lane >> 3, vlo = (lane & 7) * 16;

    auto stage = [&](int buf, int kv0) {
        #pragma unroll
        for (int j = 0; j < 4; ++j) {
            int r0 = wid * 16 + j * 4;
            int row = r0 + klr;
            gload16((const char*)Kbase + (size_t)(kv0 + row) * 256 + (klo ^ ((row & 7) << 4)),
                    &sK[buf][r0 * 128]);
        }
        #pragma unroll
        for (int j = 0; j < 4; ++j) {
            int r0 = wid * 32 + j * 8;
            int row = r0 + vlr;
            gload16((const char*)Vbase + (size_t)row * (S_LEN * 2) + (size_t)kv0 * 2 + (vlo ^ ((row & 7) << 4)),
                    &sV[buf][r0 * 64]);
        }
    };

    f32x4 oacc[8] = {};
    float m_r = -1e30f, l_r = 0.f;

    const int nt = (q0 >> 6) + 1;
    stage(0, 0);
    __syncthreads();

    for (int t = 0; t < nt; ++t) {
        const u16* sKc = sK[t & 1];
        const u16* sVc = sV[t & 1];
        if (t + 1 < nt) stage((t + 1) & 1, (t + 1) * 64);
        const int kv0 = t * 64;
        const bool masked = (t == nt - 1);

        f32x4 sf[4] = {};
        #pragma unroll
        for (int st = 0; st < 4; ++st) {
            #pragma unroll
            for (int c = 0; c < 4; ++c) {
                bf16x8 kf = *(const bf16x8*)((const char*)sKc +
                                (st * 16 + l15) * 256 + ((c * 64 + g * 16) ^ kswz));
                sf[st] = __builtin_amdgcn_mfma_f32_16x16x32_bf16(kf, qf[c], sf[st], 0, 0, 0);
            }
        }
        float p[16];
        #pragma unroll
        for (int st = 0; st < 4; ++st)
            #pragma unroll
            for (int r = 0; r < 4; ++r) p[st * 4 + r] = sf[st][r];
        if (masked) {
            #pragma unroll
            for (int st = 0; st < 4; ++st)
                #pragma unroll
                for (int r = 0; r < 4; ++r) {
                    int kp = kv0 + st * 16 + g * 4 + r;
                    if (kp > q0 + l15) p[st * 4 + r] = -1e30f;
                }
        }
        float tm = p[0];
        #pragma unroll
        for (int i = 1; i < 16; ++i) tm = fmaxf(tm, p[i]);
        tm = fmaxf(tm, __shfl_xor(tm, 16));
        tm = fmaxf(tm, __shfl_xor(tm, 32));
        // T13 defer-max: only rescale when some row's max grew by > 8 (exp2 units)
        if (!__all(tm - m_r <= 8.0f)) {
            float mn = fmaxf(m_r, tm);
            float fscale = exp2f(m_r - mn);
            m_r = mn;
            l_r *= fscale;
            #pragma unroll
            for (int ht = 0; ht < 8; ++ht) oacc[ht] *= fscale;
        }
        float rs = 0.f;
        #pragma unroll
        for (int i = 0; i < 16; ++i) { p[i] = exp2f(p[i] - m_r); rs += p[i]; }

        // P -> per-wave LDS tile (D-layout -> B-frag layout); PV-critical path first
        #pragma unroll
        for (int st = 0; st < 4; ++st) {
            uint2 w;
            w.x = pk2(p[st * 4 + 0], p[st * 4 + 1]);
            w.y = pk2(p[st * 4 + 2], p[st * 4 + 3]);
            *(uint2*)&p_sh[l15 * 36 + st * 8 + g * 2] = w;
        }
        bf16x8 pa0 = *(const bf16x8*)&p_sh[l15 * 36 + g * 4];
        bf16x8 pa1 = *(const bf16x8*)&p_sh[l15 * 36 + 16 + g * 4];

        #pragma unroll
        for (int ht = 0; ht < 8; ++ht) {
            bf16x8 v0 = *(const bf16x8*)((const char*)sVc +
                            (ht * 16 + l15) * 128 + ((g * 16) ^ kswz));
            bf16x8 v1 = *(const bf16x8*)((const char*)sVc +
                            (ht * 16 + l15) * 128 + ((64 + g * 16) ^ kswz));
            oacc[ht] = __builtin_amdgcn_mfma_f32_16x16x32_bf16(v0, pa0, oacc[ht], 0, 0, 0);
            oacc[ht] = __builtin_amdgcn_mfma_f32_16x16x32_bf16(v1, pa1, oacc[ht], 0, 0, 0);
        }
        // sum-reduce shuffles after PV: ds_permute overlaps the matrix pipe
        rs += __shfl_xor(rs, 16);
        rs += __shfl_xor(rs, 32);
        l_r += rs;
        __syncthreads();
    }

    float inv_l = 1.0f / l_r;
    #pragma unroll
    for (int ht = 0; ht < 8; ++ht) {
        uint2 o;
        o.x = pk2(oacc[ht][0] * inv_l, oacc[ht][1] * inv_l);
        o.y = pk2(oacc[ht][2] * inv_l, oacc[ht][3] * inv_l);
        *(uint2*)&Ob[(size_t)(b * S_LEN + q0 + l15) * 512 + h * 128 + ht * 16 + g * 4] = o;
    }
}

extern "C" void kernel_launch(void* const* d_in, const int* in_sizes, int n_in,
                              void* d_out, int out_size, void* d_ws, size_t ws_size,
                              hipStream_t stream) {
    const float* x         = (const float*)d_in[0];
    const int*   positions = (const int*)d_in[1];
    const float* wq        = (const float*)d_in[2];
    const float* wk        = (const float*)d_in[3];
    const float* wv        = (const float*)d_in[4];
    const float* wo        = (const float*)d_in[5];
    float* out = (float*)d_out;

    // d_out (134.2MB): [0,67.1) = Xb bf16, [67.1,79.7) = P1 bf16 (dead before GEMM2 writes)
    u16* Xb = (u16*)d_out;
    u16* P1 = (u16*)((char*)d_out + 67108864);

    char* ws = (char*)d_ws;
    size_t off = 0;
    auto alloc = [&](size_t bytes) { void* p = ws + off; off = (off + bytes + 255) & ~(size_t)255; return p; };
    u16*   Wqkv = (u16*)alloc(768ull * 4096 * 2);
    u16*   WoT  = (u16*)alloc(4096ull * 512 * 2);
    u16*   P0   = (u16*)alloc(8192ull * 768 * 2);
    u16*   Qb   = (u16*)alloc(8192ull * 512 * 2);
    u16*   Kb   = (u16*)alloc(8192ull * 128 * 2);
    u16*   Vt   = (u16*)alloc(4ull * 128 * 2048 * 2);
    u16*   Ob   = (u16*)alloc(8192ull * 512 * 2);

    conv_x_kernel<<<(8192 * 4096) / (4 * 256), 256, 0, stream>>>(x, Xb);
    pack_wqkv_kernel<<<dim3(24, 128), 256, 0, stream>>>(wq, wk, wv, Wqkv);
    pack_wo_kernel<<<dim3(128, 16), 256, 0, stream>>>(wo, WoT);

    // GEMM1 (bf16 Xb): 128^2 tile, split-K=2, z=0 -> P0, z=1 -> P1 (both bf16)
    gemm_pipe_bf<<<dim3(6, 64, 2), 256, 0, stream>>>(Xb, Wqkv, P0, P1, 768, 4096, 2048);

    rope_rms_kernel<<<(8192 * 5) / 4, 256, 0, stream>>>(P0, P1, positions, Qb, Kb);
    vtrans_kernel<<<128, 256, 0, stream>>>(P0, P1, Vt);

    attn_kernel<<<512, 256, 0, stream>>>(Qb, Kb, Vt, Ob);

    // GEMM2 (bf16 Ob) -> f32 out: 256^2 tile, 8 waves
    gemm_pipe256<<<dim3(4096 / 256, 8192 / 256), 512, 0, stream>>>(Ob, WoT, out, 4096, 512);
}